// Round 1
// baseline (483.428 us; speedup 1.0000x reference)
//
#include <hip/hip_runtime.h>

#define DIM 512
#define NH 8
#define HD 64
#define LH 4
#define WIN 64
#define BATCH 4
#define SEQ 8192
#define NWIN (SEQ/WIN)   // 128

typedef unsigned short u16;
typedef __bf16 bf16x8 __attribute__((ext_vector_type(8)));
typedef float f32x4 __attribute__((ext_vector_type(4)));

__device__ __forceinline__ float b2f(u16 u) {
    return __uint_as_float(((unsigned int)u) << 16);
}
__device__ __forceinline__ u16 f2b(float f) {
    unsigned int x = __float_as_uint(f);
    return (u16)((x + 0x7FFFu + ((x >> 16) & 1u)) >> 16);
}

// async global->LDS, 16B per lane, lands at ldsbase + lane*16
__device__ __forceinline__ void gload16(const void* g, void* l) {
    __builtin_amdgcn_global_load_lds(
        (__attribute__((address_space(1))) void*)g,
        (__attribute__((address_space(3))) void*)l, 16, 0, 0);
}

// fp32 -> bf16 conversion
__global__ void convert_bf16(const float* __restrict__ src, u16* __restrict__ dst, long n)
{
    long i = ((long)blockIdx.x * 256 + threadIdx.x) * 8;
    const long stride = (long)gridDim.x * 256 * 8;
    for (; i < n; i += stride) {
        uint4 a = *(const uint4*)(src + i), b = *(const uint4*)(src + i + 4);
        const float* af = (const float*)&a;
        const float* bf_ = (const float*)&b;
        uint4 o; u16* ou = (u16*)&o;
        #pragma unroll
        for (int j = 0; j < 4; j++) { ou[j] = f2b(af[j]); ou[4 + j] = f2b(bf_[j]); }
        *(uint4*)(dst + i) = o;
    }
}

// ---------------------------------------------------------------------------
// Kernel A: [q|k] = x @ [Wq|Wkv]^T as one M=32768 x N=1024 x K=512 GEMM.
// m97 structure: 128x128 tile, BK=32, global_load_lds(16B), 4x4 MFMA acc/wave.
// Epilogue: per-wave LDS transpose -> coalesced 128B-row stores into the
// (B,NH,SEQ,HD) head-split bf16 layouts qh / kh.
// ---------------------------------------------------------------------------
__global__ __launch_bounds__(256) void gemm_qk_tiled(const u16* __restrict__ xb,
        const u16* __restrict__ Wqk, u16* __restrict__ qh, u16* __restrict__ kh)
{
    __shared__ __align__(16) u16 smem[16384];  // 32 KB: K-loop uses 16 KB, epilogue 32 KB
    u16* lA = smem;          // [128][32]
    u16* lB = smem + 4096;   // [128][32]

    const int tid = threadIdx.x;
    const int wv = tid >> 6, lane = tid & 63;
    const int quad = lane >> 4, l16 = lane & 15;
    const int wr = wv >> 1, wc = wv & 1;
    const int row0 = blockIdx.y * 128;
    const int col0 = blockIdx.x * 128;
    const int lrow = lane >> 2, lkc = (lane & 3) * 8;

    f32x4 acc[4][4];
    #pragma unroll
    for (int t = 0; t < 4; t++)
        for (int u = 0; u < 4; u++)
            for (int i = 0; i < 4; i++) acc[t][u][i] = 0.f;

    const u16* gA = xb  + (size_t)(row0 + lrow) * DIM + lkc;
    const u16* gB = Wqk + (size_t)(col0 + lrow) * DIM + lkc;

    for (int kt = 0; kt < DIM; kt += 32) {
        __syncthreads();
        #pragma unroll
        for (int i = 0; i < 2; i++) {
            int rb = wv * 32 + i * 16;
            gload16(gA + (size_t)rb * DIM + kt, &lA[rb * 32]);
            gload16(gB + (size_t)rb * DIM + kt, &lB[rb * 32]);
        }
        __syncthreads();
        bf16x8 af[4], bfr[4];
        #pragma unroll
        for (int t = 0; t < 4; t++)
            af[t] = *(const bf16x8*)&lA[(wr * 64 + t * 16 + l16) * 32 + quad * 8];
        #pragma unroll
        for (int u = 0; u < 4; u++)
            bfr[u] = *(const bf16x8*)&lB[(wc * 64 + u * 16 + l16) * 32 + quad * 8];
        #pragma unroll
        for (int t = 0; t < 4; t++)
            #pragma unroll
            for (int u = 0; u < 4; u++)
                acc[t][u] = __builtin_amdgcn_mfma_f32_16x16x32_bf16(af[t], bfr[u], acc[t][u], 0, 0, 0);
    }

    // epilogue: wave-local 64x64 bf16 C-tile in LDS, then coalesced stores
    __syncthreads();
    u16* cw = smem + wv * 4096;
    #pragma unroll
    for (int t = 0; t < 4; t++)
        #pragma unroll
        for (int u = 0; u < 4; u++)
            #pragma unroll
            for (int r = 0; r < 4; r++)
                cw[(t * 16 + quad * 4 + r) * 64 + u * 16 + l16] = f2b(acc[t][u][r]);

    const int colg0 = col0 + wc * 64;            // wave's 64 cols = one full head
    const int seg = lane & 7;
    u16* dstbase;
    {
        int h = (colg0 & 511) >> 6;
        u16* base = (colg0 < 512) ? qh : kh;
        dstbase = base + (size_t)h * SEQ * HD;   // + b*NH*SEQ*HD later
    }
    #pragma unroll
    for (int i = 0; i < 8; i++) {
        int mm = i * 8 + (lane >> 3);
        uint4 v = *(const uint4*)&cw[mm * 64 + seg * 8];
        int m = row0 + wr * 64 + mm;
        int bb = m >> 13, nn = m & (SEQ - 1);
        *(uint4*)(dstbase + ((size_t)bb * NH * SEQ + nn) * HD + seg * 8) = v;
    }
}

// ---------------------------------------------------------------------------
// Kernel B: local attention (unchanged).
// ---------------------------------------------------------------------------
#define KJ_STRIDE 72
#define KT_STRIDE 200

__global__ __launch_bounds__(256) void local_attn(const u16* __restrict__ qh,
        const u16* __restrict__ kh, float* __restrict__ attn_out)
{
    __shared__ __align__(16) u16 kjP[192 * KJ_STRIDE];
    __shared__ __align__(16) u16 kT[64 * KT_STRIDE];

    const int w = blockIdx.x;
    const int bh = blockIdx.y;
    const int b = bh >> 2, h = bh & 3;
    const int tid = threadIdx.x;
    const int wv = tid >> 6, lane = tid & 63;
    const int quad = lane >> 4, l16 = lane & 15;

    for (int idx = tid; idx < 192 * 8; idx += 256) {
        int j = idx >> 3, dc = (idx & 7) << 3;
        int n = w * WIN - WIN + j;
        uint4 val = make_uint4(0, 0, 0, 0);
        if (n >= 0 && n < SEQ)
            val = *(const uint4*)(kh + (((size_t)(b * NH + h)) * SEQ + n) * HD + dc);
        *(uint4*)(&kjP[j * KJ_STRIDE + dc]) = val;
    }
    __syncthreads();
    for (int idx = tid; idx < 64 * 192; idx += 256) {
        int e = idx & 63, j = idx >> 6;
        kT[e * KT_STRIDE + j] = kjP[j * KJ_STRIDE + e];
    }
    __syncthreads();

    f32x4 s[12];
    #pragma unroll
    for (int t = 0; t < 12; t++)
        for (int i = 0; i < 4; i++) s[t][i] = 0.f;

    const u16* qrow = qh + (((size_t)(b * NH + h)) * SEQ + w * WIN + wv * 16 + l16) * HD + quad * 8;
    #pragma unroll
    for (int kk = 0; kk < 64; kk += 32) {
        bf16x8 a = *(const bf16x8*)(qrow + kk);
        #pragma unroll
        for (int t = 0; t < 12; t++) {
            bf16x8 bf = *(const bf16x8*)(&kjP[(t * 16 + l16) * KJ_STRIDE + kk + quad * 8]);
            s[t] = __builtin_amdgcn_mfma_f32_16x16x32_bf16(a, bf, s[t], 0, 0, 0);
        }
    }
    __syncthreads();

    const float scale = 0.125f;
    #pragma unroll
    for (int r = 0; r < 4; r++) {
        float vals[12];
        float mx = -3.0e38f;
        #pragma unroll
        for (int t = 0; t < 12; t++) {
            int j = t * 16 + l16;
            float v = s[t][r] * scale;
            bool valid = !((w == 0 && j < 64) || (w == NWIN - 1 && j >= 128));
            v = valid ? v : -30000.0f;
            vals[t] = v;
            mx = fmaxf(mx, v);
        }
        for (int m = 1; m <= 8; m <<= 1) mx = fmaxf(mx, __shfl_xor(mx, m));
        float sum = 0.f;
        #pragma unroll
        for (int t = 0; t < 12; t++) { vals[t] = __expf(vals[t] - mx); sum += vals[t]; }
        for (int m = 1; m <= 8; m <<= 1) sum += __shfl_xor(sum, m);
        float inv = 1.0f / sum;
        int prow = wv * 16 + quad * 4 + r;
        #pragma unroll
        for (int t = 0; t < 12; t++)
            kjP[prow * KT_STRIDE + t * 16 + l16] = f2b(vals[t] * inv);
    }
    __syncthreads();

    f32x4 o[4];
    #pragma unroll
    for (int t = 0; t < 4; t++)
        for (int i = 0; i < 4; i++) o[t][i] = 0.f;
    #pragma unroll
    for (int kc = 0; kc < 6; kc++) {
        bf16x8 a = *(const bf16x8*)(&kjP[(wv * 16 + l16) * KT_STRIDE + kc * 32 + quad * 8]);
        #pragma unroll
        for (int t = 0; t < 4; t++) {
            bf16x8 bf = *(const bf16x8*)(&kT[(t * 16 + l16) * KT_STRIDE + kc * 32 + quad * 8]);
            o[t] = __builtin_amdgcn_mfma_f32_16x16x32_bf16(a, bf, o[t], 0, 0, 0);
        }
    }
    #pragma unroll
    for (int t = 0; t < 4; t++) {
        int e = t * 16 + l16;
        #pragma unroll
        for (int r = 0; r < 4; r++) {
            int n = w * WIN + wv * 16 + quad * 4 + r;
            attn_out[(((size_t)(b * NH + h)) * SEQ + n) * HD + e] = o[t][r];
        }
    }
}

// ---------------------------------------------------------------------------
// Kernel C1: linear attention context accumulate — REWRITTEN.
// Old: 4-row staging, 2 barriers per 4 rows, 256 blocks (1/CU), VALUBusy 10%.
// New: 64-row staging phases (8x fewer barriers), 512 blocks (2/CU to hide
// barrier stalls), padded LDS stride 68 (conflict-free b128 writes),
// register-blocked 16 FMA/row/thread. Same fp32 numerics, same atomic tail.
// ---------------------------------------------------------------------------
__global__ __launch_bounds__(256) void ctx_accum(const u16* __restrict__ kh,
        float* __restrict__ S, float* __restrict__ colsum)
{
    const int chunk = blockIdx.x;          // 32 chunks x 256 rows
    const int bh = blockIdx.y;
    const int b = bh >> 2, hg = bh & 3;
    const int tid = threadIdx.x;
    const int d = tid >> 2, esub = tid & 3;

    __shared__ __align__(16) float kraw[64 * 68];  // stride 68: spreads b128 writes over banks
    __shared__ __align__(16) float kexp[64 * 68];

    float acc[16];
    #pragma unroll
    for (int i = 0; i < 16; i++) acc[i] = 0.f;
    float csum = 0.f;

    const u16* kbase = kh + ((size_t)(b * NH + LH + hg)) * SEQ * HD
                          + (size_t)chunk * 256 * HD;

    for (int ph = 0; ph < 4; ph++) {
        __syncthreads();
        // stage 64 rows (4096 bf16): 2 coalesced uint4 passes, exp once per elem
        #pragma unroll
        for (int pass = 0; pass < 2; pass++) {
            int idx = pass * 256 + tid;          // 0..511
            int row = idx >> 3, seg = (idx & 7) * 8;
            uint4 v = *(const uint4*)(kbase + ((size_t)(ph * 64 + row)) * HD + seg);
            const u16* u = (const u16*)&v;
            f32x4 r0, r1, e0, e1;
            #pragma unroll
            for (int j = 0; j < 4; j++) {
                r0[j] = b2f(u[j]);      e0[j] = __expf(r0[j]);
                r1[j] = b2f(u[4 + j]);  e1[j] = __expf(r1[j]);
            }
            float* kr = &kraw[row * 68 + seg];
            float* ke = &kexp[row * 68 + seg];
            *(f32x4*)kr = r0;  *(f32x4*)(kr + 4) = r1;
            *(f32x4*)ke = e0;  *(f32x4*)(ke + 4) = e1;
        }
        __syncthreads();
        // 64 rows of rank-1 update: thread owns (d, 16 e-cols)
        #pragma unroll 4
        for (int r = 0; r < 64; r++) {
            float ek = kexp[r * 68 + d];          // broadcast within quad
            csum += ek;                           // only esub==0 writes it out
            const f32x4* kv = (const f32x4*)&kraw[r * 68 + esub * 16];
            #pragma unroll
            for (int j = 0; j < 4; j++) {
                f32x4 k4 = kv[j];
                acc[j * 4 + 0] += ek * k4[0];
                acc[j * 4 + 1] += ek * k4[1];
                acc[j * 4 + 2] += ek * k4[2];
                acc[j * 4 + 3] += ek * k4[3];
            }
        }
    }

    float* Sp = S + (size_t)bh * 4096 + d * 64 + esub * 16;
    #pragma unroll
    for (int i = 0; i < 16; i++) atomicAdd(Sp + i, acc[i]);
    if (esub == 0) atomicAdd(colsum + bh * 64 + d, csum);
}

// ---------------------------------------------------------------------------
// Kernel C2: linear attention output (unchanged).
// ---------------------------------------------------------------------------
__global__ __launch_bounds__(256) void global_out(const u16* __restrict__ qh,
        const float* __restrict__ S, const float* __restrict__ colsum,
        float* __restrict__ attn_out)
{
    const int nblk = blockIdx.x;
    const int bh = blockIdx.y;
    const int b = bh >> 2, hg = bh & 3;
    const int tid = threadIdx.x;

    __shared__ float ctx[4096];
    for (int idx = tid; idx < 4096; idx += 256) {
        int dd = idx >> 6;
        ctx[idx] = S[(size_t)bh * 4096 + idx] / colsum[bh * 64 + dd];
    }
    __syncthreads();

    const int n = nblk * 256 + tid;
    const size_t rowidx = (((size_t)(b * NH + LH + hg)) * SEQ + n) * HD;
    const u16* qrow = qh + rowidx;

    float sumexp = 0.f;
    for (int c = 0; c < 8; c++) {
        uint4 v = *(const uint4*)(qrow + c * 8);
        const u16* u = (const u16*)&v;
        #pragma unroll
        for (int jj = 0; jj < 8; jj++) sumexp += __expf(b2f(u[jj]));
    }
    float inv = 0.125f / sumexp;

    f32x4 out4[16];
    #pragma unroll
    for (int t = 0; t < 16; t++)
        for (int i = 0; i < 4; i++) out4[t][i] = 0.f;

    for (int c = 0; c < 8; c++) {
        uint4 v = *(const uint4*)(qrow + c * 8);
        const u16* u = (const u16*)&v;
        #pragma unroll
        for (int jj = 0; jj < 8; jj++) {
            float pd = __expf(b2f(u[jj])) * inv;
            const f32x4* cr = (const f32x4*)&ctx[(c * 8 + jj) * 64];
            #pragma unroll
            for (int t = 0; t < 16; t++)
                out4[t] += pd * cr[t];
        }
    }

    float* ao = attn_out + rowidx;
    #pragma unroll
    for (int t = 0; t < 16; t++)
        *(f32x4*)(ao + t * 4) = out4[t];
}

// ---------------------------------------------------------------------------
// Kernel D: y = attn @ Wproj^T + bproj, LDS-tiled (unchanged).
// ---------------------------------------------------------------------------
__global__ __launch_bounds__(256) void proj_gemm_tiled(const float* __restrict__ attn_out,
        const u16* __restrict__ Wproj, const float* __restrict__ bproj,
        float* __restrict__ y)
{
    __shared__ __align__(16) u16 smem[8192];   // 16 KB: lA 8 KB + lB 8 KB
    u16* lA = smem;          // [128][32]
    u16* lB = smem + 4096;   // [128][32]

    const int tid = threadIdx.x;
    const int wv = tid >> 6, lane = tid & 63;
    const int quad = lane >> 4, l16 = lane & 15;
    const int wr = wv >> 1, wc = wv & 1;
    const int row0 = blockIdx.y * 128;
    const int col0 = blockIdx.x * 128;
    const int lrow = lane >> 2, lkc = (lane & 3) * 8;

    f32x4 acc[4][4];
    #pragma unroll
    for (int t = 0; t < 4; t++)
        for (int u = 0; u < 4; u++)
            for (int i = 0; i < 4; i++) acc[t][u][i] = 0.f;

    const u16* gB = Wproj + (size_t)(col0 + lrow) * DIM + lkc;

    for (int kt = 0; kt < DIM; kt += 32) {
        const int h = kt >> 6;               // k-chunk stays within one head
        const int e0 = (kt & 63) + lkc;
        __syncthreads();
        #pragma unroll
        for (int i = 0; i < 2; i++) {
            int rb = wv * 32 + i * 16;
            // B via async direct-to-LDS
            gload16(gB + (size_t)rb * DIM + kt, &lB[rb * 32]);
            // A: fp32 -> bf16 through registers
            int m = row0 + rb + lrow;
            int bb = m >> 13, nn = m & (SEQ - 1);
            const float* ga = attn_out + (((size_t)(bb * NH + h)) * SEQ + nn) * HD + e0;
            uint4 f0 = *(const uint4*)ga;
            uint4 f1 = *(const uint4*)(ga + 4);
            const float* a0 = (const float*)&f0;
            const float* a1 = (const float*)&f1;
            uint4 o; u16* ou = (u16*)&o;
            #pragma unroll
            for (int j = 0; j < 4; j++) { ou[j] = f2b(a0[j]); ou[4 + j] = f2b(a1[j]); }
            *(uint4*)&lA[(rb + lrow) * 32 + lkc] = o;
        }
        __syncthreads();
        bf16x8 af[4], bfr[4];
        #pragma unroll
        for (int t = 0; t < 4; t++)
            af[t] = *(const bf16x8*)&lA[(wr * 64 + t * 16 + l16) * 32 + quad * 8];
        #pragma unroll
        for (int u = 0; u < 4; u++)
            bfr[u] = *(const bf16x8*)&lB[(wc * 64 + u * 16 + l16) * 32 + quad * 8];
        #pragma unroll
        for (int t = 0; t < 4; t++)
            #pragma unroll
            for (int u = 0; u < 4; u++)
                acc[t][u] = __builtin_amdgcn_mfma_f32_16x16x32_bf16(af[t], bfr[u], acc[t][u], 0, 0, 0);
    }

    #pragma unroll
    for (int u = 0; u < 4; u++) {
        int col = col0 + wc * 64 + u * 16 + l16;
        float bias = bproj[col];
        #pragma unroll
        for (int t = 0; t < 4; t++)
            #pragma unroll
            for (int r = 0; r < 4; r++) {
                int m = row0 + wr * 64 + t * 16 + quad * 4 + r;
                y[(size_t)m * DIM + col] = acc[t][u][r] + bias;
            }
    }
}

// ---------------------------------------------------------------------------
extern "C" void kernel_launch(void* const* d_in, const int* in_sizes, int n_in,
                              void* d_out, int out_size, void* d_ws, size_t ws_size,
                              hipStream_t stream)
{
    (void)in_sizes; (void)n_in; (void)out_size; (void)ws_size;
    const float* x     = (const float*)d_in[0];
    const float* Wq    = (const float*)d_in[1];
    const float* Wkv   = (const float*)d_in[2];
    const float* Wproj = (const float*)d_in[3];
    const float* bproj = (const float*)d_in[4];

    float* y        = (float*)d_out;                         // (B,N,C) fp32
    float* attn_out = y + (size_t)BATCH * SEQ * DIM;         // (B,H,N,64) fp32

    // bf16 x and q staged in the y byte-region (consumed before proj writes y)
    u16* xb = (u16*)y;                                       // 33.5 MB
    u16* qh = xb + (size_t)BATCH * SEQ * DIM;                // 33.5 MB

    char* ws = (char*)d_ws;
    float* S       = (float*)ws;                             // 262144 B
    float* colsum  = (float*)(ws + 262144);                  // 4096 B
    u16*   Wqk     = (u16*)(ws + 266240);                    // 1024x512 bf16 = 1 MB
    u16*   Wproj_b = (u16*)(ws + 266240 + 1048576);          // 512 KB
    u16*   kh      = (u16*)(ws + 266240 + 1048576 + 524288); // 33.5 MB
    // total ws usage ≈ 35.4 MB

    const long NX = (long)BATCH * SEQ * DIM;   // 16,777,216
    const long NWT = (long)DIM * DIM;          // 262,144

    hipMemsetAsync(S, 0, 262144 + 4096, stream);
    convert_bf16<<<4096, 256, 0, stream>>>(x, xb, NX);
    convert_bf16<<<128, 256, 0, stream>>>(Wq, Wqk, NWT);          // cols 0..511   -> q
    convert_bf16<<<128, 256, 0, stream>>>(Wkv, Wqk + NWT, NWT);   // cols 512..1023-> k
    convert_bf16<<<128, 256, 0, stream>>>(Wproj, Wproj_b, NWT);

    gemm_qk_tiled<<<dim3(8, 256), 256, 0, stream>>>(xb, Wqk, qh, kh);
    local_attn<<<dim3(NWIN, 16), 256, 0, stream>>>(qh, kh, attn_out);
    ctx_accum<<<dim3(32, 16), 256, 0, stream>>>(kh, S, colsum);
    global_out<<<dim3(32, 16), 256, 0, stream>>>(qh, S, colsum, attn_out);
    proj_gemm_tiled<<<dim3(4, 256), 256, 0, stream>>>(attn_out, Wproj_b, bproj, y);
}

// Round 2
// 383.792 us; speedup vs baseline: 1.2596x; 1.2596x over previous
//
#include <hip/hip_runtime.h>

#define DIM 512
#define NH 8
#define HD 64
#define LH 4
#define WIN 64
#define BATCH 4
#define SEQ 8192
#define NWIN (SEQ/WIN)   // 128

typedef unsigned short u16;
typedef __bf16 bf16x8 __attribute__((ext_vector_type(8)));
typedef float f32x4 __attribute__((ext_vector_type(4)));

__device__ __forceinline__ float b2f(u16 u) {
    return __uint_as_float(((unsigned int)u) << 16);
}
__device__ __forceinline__ u16 f2b(float f) {
    unsigned int x = __float_as_uint(f);
    return (u16)((x + 0x7FFFu + ((x >> 16) & 1u)) >> 16);
}

// async global->LDS, 16B per lane, lands at ldsbase + lane*16
__device__ __forceinline__ void gload16(const void* g, void* l) {
    __builtin_amdgcn_global_load_lds(
        (__attribute__((address_space(1))) void*)g,
        (__attribute__((address_space(3))) void*)l, 16, 0, 0);
}

// fp32 -> bf16 conversion
__global__ void convert_bf16(const float* __restrict__ src, u16* __restrict__ dst, long n)
{
    long i = ((long)blockIdx.x * 256 + threadIdx.x) * 8;
    const long stride = (long)gridDim.x * 256 * 8;
    for (; i < n; i += stride) {
        uint4 a = *(const uint4*)(src + i), b = *(const uint4*)(src + i + 4);
        const float* af = (const float*)&a;
        const float* bf_ = (const float*)&b;
        uint4 o; u16* ou = (u16*)&o;
        #pragma unroll
        for (int j = 0; j < 4; j++) { ou[j] = f2b(af[j]); ou[4 + j] = f2b(bf_[j]); }
        *(uint4*)(dst + i) = o;
    }
}

// ---------------------------------------------------------------------------
// Kernel A: [q|k] = x @ [Wq|Wkv]^T as one M=32768 x N=1024 x K=512 GEMM.
// ---------------------------------------------------------------------------
__global__ __launch_bounds__(256) void gemm_qk_tiled(const u16* __restrict__ xb,
        const u16* __restrict__ Wqk, u16* __restrict__ qh, u16* __restrict__ kh)
{
    __shared__ __align__(16) u16 smem[16384];  // 32 KB: K-loop uses 16 KB, epilogue 32 KB
    u16* lA = smem;          // [128][32]
    u16* lB = smem + 4096;   // [128][32]

    const int tid = threadIdx.x;
    const int wv = tid >> 6, lane = tid & 63;
    const int quad = lane >> 4, l16 = lane & 15;
    const int wr = wv >> 1, wc = wv & 1;
    const int row0 = blockIdx.y * 128;
    const int col0 = blockIdx.x * 128;
    const int lrow = lane >> 2, lkc = (lane & 3) * 8;

    f32x4 acc[4][4];
    #pragma unroll
    for (int t = 0; t < 4; t++)
        for (int u = 0; u < 4; u++)
            for (int i = 0; i < 4; i++) acc[t][u][i] = 0.f;

    const u16* gA = xb  + (size_t)(row0 + lrow) * DIM + lkc;
    const u16* gB = Wqk + (size_t)(col0 + lrow) * DIM + lkc;

    for (int kt = 0; kt < DIM; kt += 32) {
        __syncthreads();
        #pragma unroll
        for (int i = 0; i < 2; i++) {
            int rb = wv * 32 + i * 16;
            gload16(gA + (size_t)rb * DIM + kt, &lA[rb * 32]);
            gload16(gB + (size_t)rb * DIM + kt, &lB[rb * 32]);
        }
        __syncthreads();
        bf16x8 af[4], bfr[4];
        #pragma unroll
        for (int t = 0; t < 4; t++)
            af[t] = *(const bf16x8*)&lA[(wr * 64 + t * 16 + l16) * 32 + quad * 8];
        #pragma unroll
        for (int u = 0; u < 4; u++)
            bfr[u] = *(const bf16x8*)&lB[(wc * 64 + u * 16 + l16) * 32 + quad * 8];
        #pragma unroll
        for (int t = 0; t < 4; t++)
            #pragma unroll
            for (int u = 0; u < 4; u++)
                acc[t][u] = __builtin_amdgcn_mfma_f32_16x16x32_bf16(af[t], bfr[u], acc[t][u], 0, 0, 0);
    }

    // epilogue: wave-local 64x64 bf16 C-tile in LDS, then coalesced stores
    __syncthreads();
    u16* cw = smem + wv * 4096;
    #pragma unroll
    for (int t = 0; t < 4; t++)
        #pragma unroll
        for (int u = 0; u < 4; u++)
            #pragma unroll
            for (int r = 0; r < 4; r++)
                cw[(t * 16 + quad * 4 + r) * 64 + u * 16 + l16] = f2b(acc[t][u][r]);

    const int colg0 = col0 + wc * 64;            // wave's 64 cols = one full head
    const int seg = lane & 7;
    u16* dstbase;
    {
        int h = (colg0 & 511) >> 6;
        u16* base = (colg0 < 512) ? qh : kh;
        dstbase = base + (size_t)h * SEQ * HD;   // + b*NH*SEQ*HD later
    }
    #pragma unroll
    for (int i = 0; i < 8; i++) {
        int mm = i * 8 + (lane >> 3);
        uint4 v = *(const uint4*)&cw[mm * 64 + seg * 8];
        int m = row0 + wr * 64 + mm;
        int bb = m >> 13, nn = m & (SEQ - 1);
        *(uint4*)(dstbase + ((size_t)bb * NH * SEQ + nn) * HD + seg * 8) = v;
    }
}

// ---------------------------------------------------------------------------
// Kernel B: local attention (unchanged).
// ---------------------------------------------------------------------------
#define KJ_STRIDE 72
#define KT_STRIDE 200

__global__ __launch_bounds__(256) void local_attn(const u16* __restrict__ qh,
        const u16* __restrict__ kh, float* __restrict__ attn_out)
{
    __shared__ __align__(16) u16 kjP[192 * KJ_STRIDE];
    __shared__ __align__(16) u16 kT[64 * KT_STRIDE];

    const int w = blockIdx.x;
    const int bh = blockIdx.y;
    const int b = bh >> 2, h = bh & 3;
    const int tid = threadIdx.x;
    const int wv = tid >> 6, lane = tid & 63;
    const int quad = lane >> 4, l16 = lane & 15;

    for (int idx = tid; idx < 192 * 8; idx += 256) {
        int j = idx >> 3, dc = (idx & 7) << 3;
        int n = w * WIN - WIN + j;
        uint4 val = make_uint4(0, 0, 0, 0);
        if (n >= 0 && n < SEQ)
            val = *(const uint4*)(kh + (((size_t)(b * NH + h)) * SEQ + n) * HD + dc);
        *(uint4*)(&kjP[j * KJ_STRIDE + dc]) = val;
    }
    __syncthreads();
    for (int idx = tid; idx < 64 * 192; idx += 256) {
        int e = idx & 63, j = idx >> 6;
        kT[e * KT_STRIDE + j] = kjP[j * KJ_STRIDE + e];
    }
    __syncthreads();

    f32x4 s[12];
    #pragma unroll
    for (int t = 0; t < 12; t++)
        for (int i = 0; i < 4; i++) s[t][i] = 0.f;

    const u16* qrow = qh + (((size_t)(b * NH + h)) * SEQ + w * WIN + wv * 16 + l16) * HD + quad * 8;
    #pragma unroll
    for (int kk = 0; kk < 64; kk += 32) {
        bf16x8 a = *(const bf16x8*)(qrow + kk);
        #pragma unroll
        for (int t = 0; t < 12; t++) {
            bf16x8 bf = *(const bf16x8*)(&kjP[(t * 16 + l16) * KJ_STRIDE + kk + quad * 8]);
            s[t] = __builtin_amdgcn_mfma_f32_16x16x32_bf16(a, bf, s[t], 0, 0, 0);
        }
    }
    __syncthreads();

    const float scale = 0.125f;
    #pragma unroll
    for (int r = 0; r < 4; r++) {
        float vals[12];
        float mx = -3.0e38f;
        #pragma unroll
        for (int t = 0; t < 12; t++) {
            int j = t * 16 + l16;
            float v = s[t][r] * scale;
            bool valid = !((w == 0 && j < 64) || (w == NWIN - 1 && j >= 128));
            v = valid ? v : -30000.0f;
            vals[t] = v;
            mx = fmaxf(mx, v);
        }
        for (int m = 1; m <= 8; m <<= 1) mx = fmaxf(mx, __shfl_xor(mx, m));
        float sum = 0.f;
        #pragma unroll
        for (int t = 0; t < 12; t++) { vals[t] = __expf(vals[t] - mx); sum += vals[t]; }
        for (int m = 1; m <= 8; m <<= 1) sum += __shfl_xor(sum, m);
        float inv = 1.0f / sum;
        int prow = wv * 16 + quad * 4 + r;
        #pragma unroll
        for (int t = 0; t < 12; t++)
            kjP[prow * KT_STRIDE + t * 16 + l16] = f2b(vals[t] * inv);
    }
    __syncthreads();

    f32x4 o[4];
    #pragma unroll
    for (int t = 0; t < 4; t++)
        for (int i = 0; i < 4; i++) o[t][i] = 0.f;
    #pragma unroll
    for (int kc = 0; kc < 6; kc++) {
        bf16x8 a = *(const bf16x8*)(&kjP[(wv * 16 + l16) * KT_STRIDE + kc * 32 + quad * 8]);
        #pragma unroll
        for (int t = 0; t < 4; t++) {
            bf16x8 bf = *(const bf16x8*)(&kT[(t * 16 + l16) * KT_STRIDE + kc * 32 + quad * 8]);
            o[t] = __builtin_amdgcn_mfma_f32_16x16x32_bf16(a, bf, o[t], 0, 0, 0);
        }
    }
    #pragma unroll
    for (int t = 0; t < 4; t++) {
        int e = t * 16 + l16;
        #pragma unroll
        for (int r = 0; r < 4; r++) {
            int n = w * WIN + wv * 16 + quad * 4 + r;
            attn_out[(((size_t)(b * NH + h)) * SEQ + n) * HD + e] = o[t][r];
        }
    }
}

// ---------------------------------------------------------------------------
// Kernel C1: linear attention context accumulate — register-blocked, no S atomics.
// Thread owns 4d x 16e (64 acc VGPRs); one wave covers the full 64x64 outer
// product per row; waves take disjoint rows. Per row: 5 ds_read_b128 -> 64
// independent FMAs (4x the ILP of R1). Block partial written with plain
// stores to `partials` (scratch in attn_out b0 global-head region); only
// colsum (64 floats/block) uses atomics. 3-barrier LDS tree combines waves.
// ---------------------------------------------------------------------------
__global__ __launch_bounds__(256) void ctx_accum(const u16* __restrict__ kh,
        float* __restrict__ partials, float* __restrict__ colsum)
{
    const int chunk = blockIdx.x;          // 32 chunks x 256 rows
    const int bh = blockIdx.y;
    const int b = bh >> 2, hg = bh & 3;
    const int tid = threadIdx.x;
    const int wv = tid >> 6, lane = tid & 63;
    const int d0 = (lane >> 2) * 4;        // 16 d-groups of 4
    const int e0 = (lane & 3) * 16;        // 4 e-groups of 16

    __shared__ __align__(16) float smem[2 * 64 * 68];   // 34,816 B
    float* kraw = smem;
    float* kexp = smem + 64 * 68;

    f32x4 acc[4][4];
    #pragma unroll
    for (int dd = 0; dd < 4; dd++)
        #pragma unroll
        for (int j = 0; j < 4; j++)
            for (int i = 0; i < 4; i++) acc[dd][j][i] = 0.f;
    f32x4 csum;
    for (int i = 0; i < 4; i++) csum[i] = 0.f;

    const u16* kbase = kh + ((size_t)(b * NH + LH + hg)) * SEQ * HD
                          + (size_t)chunk * 256 * HD;

    for (int ph = 0; ph < 4; ph++) {
        __syncthreads();
        // stage 64 rows: raw + exp, padded stride 68
        #pragma unroll
        for (int pass = 0; pass < 2; pass++) {
            int idx = pass * 256 + tid;
            int row = idx >> 3, seg = (idx & 7) * 8;
            uint4 v = *(const uint4*)(kbase + ((size_t)(ph * 64 + row)) * HD + seg);
            const u16* u = (const u16*)&v;
            f32x4 r0, r1, E0, E1;
            #pragma unroll
            for (int j = 0; j < 4; j++) {
                r0[j] = b2f(u[j]);      E0[j] = __expf(r0[j]);
                r1[j] = b2f(u[4 + j]);  E1[j] = __expf(r1[j]);
            }
            float* kr = &kraw[row * 68 + seg];
            float* ke = &kexp[row * 68 + seg];
            *(f32x4*)kr = r0;  *(f32x4*)(kr + 4) = r1;
            *(f32x4*)ke = E0;  *(f32x4*)(ke + 4) = E1;
        }
        __syncthreads();
        // each wave: 16 disjoint rows, full 64x64 rank-1 updates
        #pragma unroll 4
        for (int i = 0; i < 16; i++) {
            int roff = (wv * 16 + i) * 68;
            f32x4 ek = *(const f32x4*)&kexp[roff + d0];
            const f32x4* kv = (const f32x4*)&kraw[roff + e0];
            f32x4 k0 = kv[0], k1 = kv[1], k2 = kv[2], k3 = kv[3];
            csum += ek;
            #pragma unroll
            for (int dd = 0; dd < 4; dd++) {
                acc[dd][0] += ek[dd] * k0;
                acc[dd][1] += ek[dd] * k1;
                acc[dd][2] += ek[dd] * k2;
                acc[dd][3] += ek[dd] * k3;
            }
        }
    }

    // cross-wave tree reduction (reuse smem; all LDS reads of kraw/kexp done)
    float* red0 = smem;          // [4160]
    float* red1 = smem + 4160;   // [4160]
    __syncthreads();
    if (wv >= 2) {
        float* rd = (wv == 2) ? red0 : red1;
        #pragma unroll
        for (int dd = 0; dd < 4; dd++)
            #pragma unroll
            for (int j = 0; j < 4; j++)
                *(f32x4*)&rd[(d0 + dd) * 64 + e0 + j * 4] = acc[dd][j];
        if ((lane & 3) == 0) *(f32x4*)&rd[4096 + d0] = csum;
    }
    __syncthreads();
    if (wv < 2) {
        float* rd = (wv == 0) ? red0 : red1;
        #pragma unroll
        for (int dd = 0; dd < 4; dd++)
            #pragma unroll
            for (int j = 0; j < 4; j++)
                acc[dd][j] += *(const f32x4*)&rd[(d0 + dd) * 64 + e0 + j * 4];
        csum += *(const f32x4*)&rd[4096 + d0];
    }
    __syncthreads();
    if (wv == 1) {
        #pragma unroll
        for (int dd = 0; dd < 4; dd++)
            #pragma unroll
            for (int j = 0; j < 4; j++)
                *(f32x4*)&red0[(d0 + dd) * 64 + e0 + j * 4] = acc[dd][j];
        if ((lane & 3) == 0) *(f32x4*)&red0[4096 + d0] = csum;
    }
    __syncthreads();
    if (wv == 0) {
        float* P = partials + ((size_t)(chunk * 16 + bh)) * 4096;
        #pragma unroll
        for (int dd = 0; dd < 4; dd++)
            #pragma unroll
            for (int j = 0; j < 4; j++) {
                f32x4 r = acc[dd][j] + *(const f32x4*)&red0[(d0 + dd) * 64 + e0 + j * 4];
                *(f32x4*)&P[(d0 + dd) * 64 + e0 + j * 4] = r;
            }
        if ((lane & 3) == 0) {
            f32x4 cs = csum + *(const f32x4*)&red0[4096 + d0];
            #pragma unroll
            for (int dd = 0; dd < 4; dd++)
                atomicAdd(colsum + bh * 64 + d0 + dd, cs[dd]);
        }
    }
}

// ---------------------------------------------------------------------------
// Kernel C1b: fold 32 partials per bh + colsum division -> final ctx (fp32).
// ---------------------------------------------------------------------------
__global__ __launch_bounds__(256) void reduce_ctx(const float* __restrict__ partials,
        const float* __restrict__ colsum, float* __restrict__ ctx)
{
    const int quarter = blockIdx.x;        // 4 x 1024 idx
    const int bh = blockIdx.y;
    const int tid = threadIdx.x;
    __shared__ float cs[64];
    if (tid < 64) cs[tid] = colsum[bh * 64 + tid];
    __syncthreads();
    const int i0 = quarter * 1024;
    for (int idx = i0 + tid; idx < i0 + 1024; idx += 256) {
        float s = 0.f;
        #pragma unroll 8
        for (int c = 0; c < 32; c++)
            s += partials[((size_t)(c * 16 + bh)) * 4096 + idx];
        ctx[(size_t)bh * 4096 + idx] = s / cs[idx >> 6];
    }
}

// ---------------------------------------------------------------------------
// Kernel C2: linear attention output (ctx precomputed; no division here).
// ---------------------------------------------------------------------------
__global__ __launch_bounds__(256) void global_out(const u16* __restrict__ qh,
        const float* __restrict__ ctxg, float* __restrict__ attn_out)
{
    const int nblk = blockIdx.x;
    const int bh = blockIdx.y;
    const int b = bh >> 2, hg = bh & 3;
    const int tid = threadIdx.x;

    __shared__ float ctx[4096];
    for (int idx = tid; idx < 4096; idx += 256)
        ctx[idx] = ctxg[(size_t)bh * 4096 + idx];
    __syncthreads();

    const int n = nblk * 256 + tid;
    const size_t rowidx = (((size_t)(b * NH + LH + hg)) * SEQ + n) * HD;
    const u16* qrow = qh + rowidx;

    float sumexp = 0.f;
    for (int c = 0; c < 8; c++) {
        uint4 v = *(const uint4*)(qrow + c * 8);
        const u16* u = (const u16*)&v;
        #pragma unroll
        for (int jj = 0; jj < 8; jj++) sumexp += __expf(b2f(u[jj]));
    }
    float inv = 0.125f / sumexp;

    f32x4 out4[16];
    #pragma unroll
    for (int t = 0; t < 16; t++)
        for (int i = 0; i < 4; i++) out4[t][i] = 0.f;

    for (int c = 0; c < 8; c++) {
        uint4 v = *(const uint4*)(qrow + c * 8);
        const u16* u = (const u16*)&v;
        #pragma unroll
        for (int jj = 0; jj < 8; jj++) {
            float pd = __expf(b2f(u[jj])) * inv;
            const f32x4* cr = (const f32x4*)&ctx[(c * 8 + jj) * 64];
            #pragma unroll
            for (int t = 0; t < 16; t++)
                out4[t] += pd * cr[t];
        }
    }

    float* ao = attn_out + rowidx;
    #pragma unroll
    for (int t = 0; t < 16; t++)
        *(f32x4*)(ao + t * 4) = out4[t];
}

// ---------------------------------------------------------------------------
// Kernel D: y = attn @ Wproj^T + bproj, LDS-tiled (unchanged).
// ---------------------------------------------------------------------------
__global__ __launch_bounds__(256) void proj_gemm_tiled(const float* __restrict__ attn_out,
        const u16* __restrict__ Wproj, const float* __restrict__ bproj,
        float* __restrict__ y)
{
    __shared__ __align__(16) u16 smem[8192];   // 16 KB: lA 8 KB + lB 8 KB
    u16* lA = smem;          // [128][32]
    u16* lB = smem + 4096;   // [128][32]

    const int tid = threadIdx.x;
    const int wv = tid >> 6, lane = tid & 63;
    const int quad = lane >> 4, l16 = lane & 15;
    const int wr = wv >> 1, wc = wv & 1;
    const int row0 = blockIdx.y * 128;
    const int col0 = blockIdx.x * 128;
    const int lrow = lane >> 2, lkc = (lane & 3) * 8;

    f32x4 acc[4][4];
    #pragma unroll
    for (int t = 0; t < 4; t++)
        for (int u = 0; u < 4; u++)
            for (int i = 0; i < 4; i++) acc[t][u][i] = 0.f;

    const u16* gB = Wproj + (size_t)(col0 + lrow) * DIM + lkc;

    for (int kt = 0; kt < DIM; kt += 32) {
        const int h = kt >> 6;               // k-chunk stays within one head
        const int e0 = (kt & 63) + lkc;
        __syncthreads();
        #pragma unroll
        for (int i = 0; i < 2; i++) {
            int rb = wv * 32 + i * 16;
            // B via async direct-to-LDS
            gload16(gB + (size_t)rb * DIM + kt, &lB[rb * 32]);
            // A: fp32 -> bf16 through registers
            int m = row0 + rb + lrow;
            int bb = m >> 13, nn = m & (SEQ - 1);
            const float* ga = attn_out + (((size_t)(bb * NH + h)) * SEQ + nn) * HD + e0;
            uint4 f0 = *(const uint4*)ga;
            uint4 f1 = *(const uint4*)(ga + 4);
            const float* a0 = (const float*)&f0;
            const float* a1 = (const float*)&f1;
            uint4 o; u16* ou = (u16*)&o;
            #pragma unroll
            for (int j = 0; j < 4; j++) { ou[j] = f2b(a0[j]); ou[4 + j] = f2b(a1[j]); }
            *(uint4*)&lA[(rb + lrow) * 32 + lkc] = o;
        }
        __syncthreads();
        bf16x8 af[4], bfr[4];
        #pragma unroll
        for (int t = 0; t < 4; t++)
            af[t] = *(const bf16x8*)&lA[(wr * 64 + t * 16 + l16) * 32 + quad * 8];
        #pragma unroll
        for (int u = 0; u < 4; u++)
            bfr[u] = *(const bf16x8*)&lB[(wc * 64 + u * 16 + l16) * 32 + quad * 8];
        #pragma unroll
        for (int t = 0; t < 4; t++)
            #pragma unroll
            for (int u = 0; u < 4; u++)
                acc[t][u] = __builtin_amdgcn_mfma_f32_16x16x32_bf16(af[t], bfr[u], acc[t][u], 0, 0, 0);
    }

    #pragma unroll
    for (int u = 0; u < 4; u++) {
        int col = col0 + wc * 64 + u * 16 + l16;
        float bias = bproj[col];
        #pragma unroll
        for (int t = 0; t < 4; t++)
            #pragma unroll
            for (int r = 0; r < 4; r++) {
                int m = row0 + wr * 64 + t * 16 + quad * 4 + r;
                y[(size_t)m * DIM + col] = acc[t][u][r] + bias;
            }
    }
}

// ---------------------------------------------------------------------------
extern "C" void kernel_launch(void* const* d_in, const int* in_sizes, int n_in,
                              void* d_out, int out_size, void* d_ws, size_t ws_size,
                              hipStream_t stream)
{
    (void)in_sizes; (void)n_in; (void)out_size; (void)ws_size;
    const float* x     = (const float*)d_in[0];
    const float* Wq    = (const float*)d_in[1];
    const float* Wkv   = (const float*)d_in[2];
    const float* Wproj = (const float*)d_in[3];
    const float* bproj = (const float*)d_in[4];

    float* y        = (float*)d_out;                         // (B,N,C) fp32
    float* attn_out = y + (size_t)BATCH * SEQ * DIM;         // (B,H,N,64) fp32

    // bf16 x and q staged in the y byte-region (consumed before proj writes y)
    u16* xb = (u16*)y;                                       // 33.5 MB
    u16* qh = xb + (size_t)BATCH * SEQ * DIM;                // 33.5 MB

    // partials scratch: batch-0 global-head slice of attn_out (8,388,608 B
    // = exactly 32 chunks x 16 bh x 4096 fp32). Dead until global_out
    // overwrites it, which happens after reduce_ctx has consumed it.
    float* partials = attn_out + (size_t)LH * SEQ * HD;

    char* ws = (char*)d_ws;
    float* S       = (float*)ws;                             // 262144 B (final ctx)
    float* colsum  = (float*)(ws + 262144);                  // 4096 B
    u16*   Wqk     = (u16*)(ws + 266240);                    // 1024x512 bf16 = 1 MB
    u16*   Wproj_b = (u16*)(ws + 266240 + 1048576);          // 512 KB
    u16*   kh      = (u16*)(ws + 266240 + 1048576 + 524288); // 33.5 MB

    const long NX = (long)BATCH * SEQ * DIM;   // 16,777,216
    const long NWT = (long)DIM * DIM;          // 262,144

    hipMemsetAsync(colsum, 0, 4096, stream);
    convert_bf16<<<4096, 256, 0, stream>>>(x, xb, NX);
    convert_bf16<<<128, 256, 0, stream>>>(Wq, Wqk, NWT);          // cols 0..511   -> q
    convert_bf16<<<128, 256, 0, stream>>>(Wkv, Wqk + NWT, NWT);   // cols 512..1023-> k
    convert_bf16<<<128, 256, 0, stream>>>(Wproj, Wproj_b, NWT);

    gemm_qk_tiled<<<dim3(8, 256), 256, 0, stream>>>(xb, Wqk, qh, kh);
    local_attn<<<dim3(NWIN, 16), 256, 0, stream>>>(qh, kh, attn_out);
    ctx_accum<<<dim3(32, 16), 256, 0, stream>>>(kh, partials, colsum);
    reduce_ctx<<<dim3(4, 16), 256, 0, stream>>>(partials, colsum, S);
    global_out<<<dim3(32, 16), 256, 0, stream>>>(qh, S, attn_out);
    proj_gemm_tiled<<<dim3(4, 256), 256, 0, stream>>>(attn_out, Wproj_b, bproj, y);
}

// Round 4
// 368.234 us; speedup vs baseline: 1.3128x; 1.0423x over previous
//
#include <hip/hip_runtime.h>

#define DIM 512
#define NH 8
#define HD 64
#define LH 4
#define WIN 64
#define BATCH 4
#define SEQ 8192
#define NWIN (SEQ/WIN)   // 128

typedef unsigned short u16;
typedef __bf16 bf16x8 __attribute__((ext_vector_type(8)));
typedef float f32x4 __attribute__((ext_vector_type(4)));

__device__ __forceinline__ float b2f(u16 u) {
    return __uint_as_float(((unsigned int)u) << 16);
}
__device__ __forceinline__ u16 f2b(float f) {
    unsigned int x = __float_as_uint(f);
    return (u16)((x + 0x7FFFu + ((x >> 16) & 1u)) >> 16);
}

// async global->LDS, 16B per lane, lands at ldsbase + lane*16
__device__ __forceinline__ void gload16(const void* g, void* l) {
    __builtin_amdgcn_global_load_lds(
        (__attribute__((address_space(1))) void*)g,
        (__attribute__((address_space(3))) void*)l, 16, 0, 0);
}

// fp32 -> bf16 conversion (x)
__global__ void convert_bf16(const float* __restrict__ src, u16* __restrict__ dst, long n)
{
    long i = ((long)blockIdx.x * 256 + threadIdx.x) * 8;
    const long stride = (long)gridDim.x * 256 * 8;
    for (; i < n; i += stride) {
        uint4 a = *(const uint4*)(src + i), b = *(const uint4*)(src + i + 4);
        const float* af = (const float*)&a;
        const float* bf_ = (const float*)&b;
        uint4 o; u16* ou = (u16*)&o;
        #pragma unroll
        for (int j = 0; j < 4; j++) { ou[j] = f2b(af[j]); ou[4 + j] = f2b(bf_[j]); }
        *(uint4*)(dst + i) = o;
    }
}

// all three weight matrices in one launch: grid.y = slice
__global__ void convert_w3(const float* __restrict__ Wq, const float* __restrict__ Wkv,
                           const float* __restrict__ Wp, u16* __restrict__ Wqk,
                           u16* __restrict__ Wproj_b)
{
    const int slice = blockIdx.y;
    const float* src = (slice == 0) ? Wq : (slice == 1) ? Wkv : Wp;
    u16* dst = (slice == 0) ? Wqk : (slice == 1) ? (Wqk + DIM * DIM) : Wproj_b;
    long i = ((long)blockIdx.x * 256 + threadIdx.x) * 8;
    if (i >= (long)DIM * DIM) return;
    uint4 a = *(const uint4*)(src + i), b = *(const uint4*)(src + i + 4);
    const float* af = (const float*)&a;
    const float* bf_ = (const float*)&b;
    uint4 o; u16* ou = (u16*)&o;
    #pragma unroll
    for (int j = 0; j < 4; j++) { ou[j] = f2b(af[j]); ou[4 + j] = f2b(bf_[j]); }
    *(uint4*)(dst + i) = o;
}

// ---------------------------------------------------------------------------
// Kernel A: [q|k] = x @ [Wq|Wkv]^T as one M=32768 x N=1024 x K=512 GEMM.
// ---------------------------------------------------------------------------
__global__ __launch_bounds__(256) void gemm_qk_tiled(const u16* __restrict__ xb,
        const u16* __restrict__ Wqk, u16* __restrict__ qh, u16* __restrict__ kh)
{
    __shared__ __align__(16) u16 smem[16384];  // 32 KB: K-loop uses 16 KB, epilogue 32 KB
    u16* lA = smem;          // [128][32]
    u16* lB = smem + 4096;   // [128][32]

    const int tid = threadIdx.x;
    const int wv = tid >> 6, lane = tid & 63;
    const int quad = lane >> 4, l16 = lane & 15;
    const int wr = wv >> 1, wc = wv & 1;
    const int row0 = blockIdx.y * 128;
    const int col0 = blockIdx.x * 128;
    const int lrow = lane >> 2, lkc = (lane & 3) * 8;

    f32x4 acc[4][4];
    #pragma unroll
    for (int t = 0; t < 4; t++)
        for (int u = 0; u < 4; u++)
            for (int i = 0; i < 4; i++) acc[t][u][i] = 0.f;

    const u16* gA = xb  + (size_t)(row0 + lrow) * DIM + lkc;
    const u16* gB = Wqk + (size_t)(col0 + lrow) * DIM + lkc;

    for (int kt = 0; kt < DIM; kt += 32) {
        __syncthreads();
        #pragma unroll
        for (int i = 0; i < 2; i++) {
            int rb = wv * 32 + i * 16;
            gload16(gA + (size_t)rb * DIM + kt, &lA[rb * 32]);
            gload16(gB + (size_t)rb * DIM + kt, &lB[rb * 32]);
        }
        __syncthreads();
        bf16x8 af[4], bfr[4];
        #pragma unroll
        for (int t = 0; t < 4; t++)
            af[t] = *(const bf16x8*)&lA[(wr * 64 + t * 16 + l16) * 32 + quad * 8];
        #pragma unroll
        for (int u = 0; u < 4; u++)
            bfr[u] = *(const bf16x8*)&lB[(wc * 64 + u * 16 + l16) * 32 + quad * 8];
        #pragma unroll
        for (int t = 0; t < 4; t++)
            #pragma unroll
            for (int u = 0; u < 4; u++)
                acc[t][u] = __builtin_amdgcn_mfma_f32_16x16x32_bf16(af[t], bfr[u], acc[t][u], 0, 0, 0);
    }

    // epilogue: wave-local 64x64 bf16 C-tile in LDS, then coalesced stores
    __syncthreads();
    u16* cw = smem + wv * 4096;
    #pragma unroll
    for (int t = 0; t < 4; t++)
        #pragma unroll
        for (int u = 0; u < 4; u++)
            #pragma unroll
            for (int r = 0; r < 4; r++)
                cw[(t * 16 + quad * 4 + r) * 64 + u * 16 + l16] = f2b(acc[t][u][r]);

    const int colg0 = col0 + wc * 64;            // wave's 64 cols = one full head
    const int seg = lane & 7;
    u16* dstbase;
    {
        int h = (colg0 & 511) >> 6;
        u16* base = (colg0 < 512) ? qh : kh;
        dstbase = base + (size_t)h * SEQ * HD;   // + b*NH*SEQ*HD later
    }
    #pragma unroll
    for (int i = 0; i < 8; i++) {
        int mm = i * 8 + (lane >> 3);
        uint4 v = *(const uint4*)&cw[mm * 64 + seg * 8];
        int m = row0 + wr * 64 + mm;
        int bb = m >> 13, nn = m & (SEQ - 1);
        *(uint4*)(dstbase + ((size_t)bb * NH * SEQ + nn) * HD + seg * 8) = v;
    }
}

// ---------------------------------------------------------------------------
// Kernel B: local attention. Also emits bf16 attn in y-layout (attn_b)
// for the projection GEMM, staged through the free kT LDS for coalescing.
// ---------------------------------------------------------------------------
#define KJ_STRIDE 72
#define KT_STRIDE 200
#define OT_STRIDE 80   // bf16 o-tile stride: 160 B rows keep uint4 alignment

__global__ __launch_bounds__(256) void local_attn(const u16* __restrict__ qh,
        const u16* __restrict__ kh, float* __restrict__ attn_out,
        u16* __restrict__ attn_b)
{
    __shared__ __align__(16) u16 kjP[192 * KJ_STRIDE];
    __shared__ __align__(16) u16 kT[64 * KT_STRIDE];

    const int w = blockIdx.x;
    const int bh = blockIdx.y;
    const int b = bh >> 2, h = bh & 3;
    const int tid = threadIdx.x;
    const int wv = tid >> 6, lane = tid & 63;
    const int quad = lane >> 4, l16 = lane & 15;

    for (int idx = tid; idx < 192 * 8; idx += 256) {
        int j = idx >> 3, dc = (idx & 7) << 3;
        int n = w * WIN - WIN + j;
        uint4 val = make_uint4(0, 0, 0, 0);
        if (n >= 0 && n < SEQ)
            val = *(const uint4*)(kh + (((size_t)(b * NH + h)) * SEQ + n) * HD + dc);
        *(uint4*)(&kjP[j * KJ_STRIDE + dc]) = val;
    }
    __syncthreads();
    for (int idx = tid; idx < 64 * 192; idx += 256) {
        int e = idx & 63, j = idx >> 6;
        kT[e * KT_STRIDE + j] = kjP[j * KJ_STRIDE + e];
    }
    __syncthreads();

    f32x4 s[12];
    #pragma unroll
    for (int t = 0; t < 12; t++)
        for (int i = 0; i < 4; i++) s[t][i] = 0.f;

    const u16* qrow = qh + (((size_t)(b * NH + h)) * SEQ + w * WIN + wv * 16 + l16) * HD + quad * 8;
    #pragma unroll
    for (int kk = 0; kk < 64; kk += 32) {
        bf16x8 a = *(const bf16x8*)(qrow + kk);
        #pragma unroll
        for (int t = 0; t < 12; t++) {
            bf16x8 bf = *(const bf16x8*)(&kjP[(t * 16 + l16) * KJ_STRIDE + kk + quad * 8]);
            s[t] = __builtin_amdgcn_mfma_f32_16x16x32_bf16(a, bf, s[t], 0, 0, 0);
        }
    }
    __syncthreads();

    const float scale = 0.125f;
    #pragma unroll
    for (int r = 0; r < 4; r++) {
        float vals[12];
        float mx = -3.0e38f;
        #pragma unroll
        for (int t = 0; t < 12; t++) {
            int j = t * 16 + l16;
            float v = s[t][r] * scale;
            bool valid = !((w == 0 && j < 64) || (w == NWIN - 1 && j >= 128));
            v = valid ? v : -30000.0f;
            vals[t] = v;
            mx = fmaxf(mx, v);
        }
        for (int m = 1; m <= 8; m <<= 1) mx = fmaxf(mx, __shfl_xor(mx, m));
        float sum = 0.f;
        #pragma unroll
        for (int t = 0; t < 12; t++) { vals[t] = __expf(vals[t] - mx); sum += vals[t]; }
        for (int m = 1; m <= 8; m <<= 1) sum += __shfl_xor(sum, m);
        float inv = 1.0f / sum;
        int prow = wv * 16 + quad * 4 + r;
        #pragma unroll
        for (int t = 0; t < 12; t++)
            kjP[prow * KT_STRIDE + t * 16 + l16] = f2b(vals[t] * inv);
    }
    __syncthreads();

    f32x4 o[4];
    #pragma unroll
    for (int t = 0; t < 4; t++)
        for (int i = 0; i < 4; i++) o[t][i] = 0.f;
    #pragma unroll
    for (int kc = 0; kc < 6; kc++) {
        bf16x8 a = *(const bf16x8*)(&kjP[(wv * 16 + l16) * KT_STRIDE + kc * 32 + quad * 8]);
        #pragma unroll
        for (int t = 0; t < 4; t++) {
            bf16x8 bf = *(const bf16x8*)(&kT[(t * 16 + l16) * KT_STRIDE + kc * 32 + quad * 8]);
            o[t] = __builtin_amdgcn_mfma_f32_16x16x32_bf16(a, bf, o[t], 0, 0, 0);
        }
    }
    // fp32 attn output (required result tensor)
    #pragma unroll
    for (int t = 0; t < 4; t++) {
        int e = t * 16 + l16;
        #pragma unroll
        for (int r = 0; r < 4; r++) {
            int n = w * WIN + wv * 16 + quad * 4 + r;
            attn_out[(((size_t)(b * NH + h)) * SEQ + n) * HD + e] = o[t][r];
        }
    }
    // bf16 copy in y-layout for proj GEMM: stage 64x64 tile in kT (now free)
    __syncthreads();
    #pragma unroll
    for (int t = 0; t < 4; t++)
        #pragma unroll
        for (int r = 0; r < 4; r++)
            kT[(wv * 16 + quad * 4 + r) * OT_STRIDE + t * 16 + l16] = f2b(o[t][r]);
    __syncthreads();
    for (int idx = tid; idx < 512; idx += 256) {
        int row = idx >> 3, seg = (idx & 7) * 8;
        uint4 v = *(const uint4*)&kT[row * OT_STRIDE + seg];
        *(uint4*)(attn_b + ((size_t)(b * SEQ + w * WIN + row)) * DIM + h * HD + seg) = v;
    }
}

// ---------------------------------------------------------------------------
// Kernel C1: linear attention context accumulate (unchanged from R2).
// ---------------------------------------------------------------------------
__global__ __launch_bounds__(256) void ctx_accum(const u16* __restrict__ kh,
        float* __restrict__ partials, float* __restrict__ colsum)
{
    const int chunk = blockIdx.x;          // 32 chunks x 256 rows
    const int bh = blockIdx.y;
    const int b = bh >> 2, hg = bh & 3;
    const int tid = threadIdx.x;
    const int wv = tid >> 6, lane = tid & 63;
    const int d0 = (lane >> 2) * 4;        // 16 d-groups of 4
    const int e0 = (lane & 3) * 16;        // 4 e-groups of 16

    __shared__ __align__(16) float smem[2 * 64 * 68];   // 34,816 B
    float* kraw = smem;
    float* kexp = smem + 64 * 68;

    f32x4 acc[4][4];
    #pragma unroll
    for (int dd = 0; dd < 4; dd++)
        #pragma unroll
        for (int j = 0; j < 4; j++)
            for (int i = 0; i < 4; i++) acc[dd][j][i] = 0.f;
    f32x4 csum;
    for (int i = 0; i < 4; i++) csum[i] = 0.f;

    const u16* kbase = kh + ((size_t)(b * NH + LH + hg)) * SEQ * HD
                          + (size_t)chunk * 256 * HD;

    for (int ph = 0; ph < 4; ph++) {
        __syncthreads();
        #pragma unroll
        for (int pass = 0; pass < 2; pass++) {
            int idx = pass * 256 + tid;
            int row = idx >> 3, seg = (idx & 7) * 8;
            uint4 v = *(const uint4*)(kbase + ((size_t)(ph * 64 + row)) * HD + seg);
            const u16* u = (const u16*)&v;
            f32x4 r0, r1, E0, E1;
            #pragma unroll
            for (int j = 0; j < 4; j++) {
                r0[j] = b2f(u[j]);      E0[j] = __expf(r0[j]);
                r1[j] = b2f(u[4 + j]);  E1[j] = __expf(r1[j]);
            }
            float* kr = &kraw[row * 68 + seg];
            float* ke = &kexp[row * 68 + seg];
            *(f32x4*)kr = r0;  *(f32x4*)(kr + 4) = r1;
            *(f32x4*)ke = E0;  *(f32x4*)(ke + 4) = E1;
        }
        __syncthreads();
        #pragma unroll 4
        for (int i = 0; i < 16; i++) {
            int roff = (wv * 16 + i) * 68;
            f32x4 ek = *(const f32x4*)&kexp[roff + d0];
            const f32x4* kv = (const f32x4*)&kraw[roff + e0];
            f32x4 k0 = kv[0], k1 = kv[1], k2 = kv[2], k3 = kv[3];
            csum += ek;
            #pragma unroll
            for (int dd = 0; dd < 4; dd++) {
                acc[dd][0] += ek[dd] * k0;
                acc[dd][1] += ek[dd] * k1;
                acc[dd][2] += ek[dd] * k2;
                acc[dd][3] += ek[dd] * k3;
            }
        }
    }

    // cross-wave tree reduction (reuse smem)
    float* red0 = smem;          // [4160]
    float* red1 = smem + 4160;   // [4160]
    __syncthreads();
    if (wv >= 2) {
        float* rd = (wv == 2) ? red0 : red1;
        #pragma unroll
        for (int dd = 0; dd < 4; dd++)
            #pragma unroll
            for (int j = 0; j < 4; j++)
                *(f32x4*)&rd[(d0 + dd) * 64 + e0 + j * 4] = acc[dd][j];
        if ((lane & 3) == 0) *(f32x4*)&rd[4096 + d0] = csum;
    }
    __syncthreads();
    if (wv < 2) {
        float* rd = (wv == 0) ? red0 : red1;
        #pragma unroll
        for (int dd = 0; dd < 4; dd++)
            #pragma unroll
            for (int j = 0; j < 4; j++)
                acc[dd][j] += *(const f32x4*)&rd[(d0 + dd) * 64 + e0 + j * 4];
        csum += *(const f32x4*)&rd[4096 + d0];
    }
    __syncthreads();
    if (wv == 1) {
        #pragma unroll
        for (int dd = 0; dd < 4; dd++)
            #pragma unroll
            for (int j = 0; j < 4; j++)
                *(f32x4*)&red0[(d0 + dd) * 64 + e0 + j * 4] = acc[dd][j];
        if ((lane & 3) == 0) *(f32x4*)&red0[4096 + d0] = csum;
    }
    __syncthreads();
    if (wv == 0) {
        float* P = partials + ((size_t)(chunk * 16 + bh)) * 4096;
        #pragma unroll
        for (int dd = 0; dd < 4; dd++)
            #pragma unroll
            for (int j = 0; j < 4; j++) {
                f32x4 r = acc[dd][j] + *(const f32x4*)&red0[(d0 + dd) * 64 + e0 + j * 4];
                *(f32x4*)&P[(d0 + dd) * 64 + e0 + j * 4] = r;
            }
        if ((lane & 3) == 0) {
            f32x4 cs = csum + *(const f32x4*)&red0[4096 + d0];
            #pragma unroll
            for (int dd = 0; dd < 4; dd++)
                atomicAdd(colsum + bh * 64 + d0 + dd, cs[dd]);
        }
    }
}

// ---------------------------------------------------------------------------
// Kernel C1b: fold 32 partials per bh + colsum division -> final ctx (fp32).
// ---------------------------------------------------------------------------
__global__ __launch_bounds__(256) void reduce_ctx(const float* __restrict__ partials,
        const float* __restrict__ colsum, float* __restrict__ ctx)
{
    const int quarter = blockIdx.x;        // 4 x 1024 idx
    const int bh = blockIdx.y;
    const int tid = threadIdx.x;
    __shared__ float cs[64];
    if (tid < 64) cs[tid] = colsum[bh * 64 + tid];
    __syncthreads();
    const int i0 = quarter * 1024;
    for (int idx = i0 + tid; idx < i0 + 1024; idx += 256) {
        float s = 0.f;
        #pragma unroll 8
        for (int c = 0; c < 32; c++)
            s += partials[((size_t)(c * 16 + bh)) * 4096 + idx];
        ctx[(size_t)bh * 4096 + idx] = s / cs[idx >> 6];
    }
}

// ---------------------------------------------------------------------------
// Kernel C2: linear attention output. Also emits bf16 attn_b copy.
// ---------------------------------------------------------------------------
__global__ __launch_bounds__(256) void global_out(const u16* __restrict__ qh,
        const float* __restrict__ ctxg, float* __restrict__ attn_out,
        u16* __restrict__ attn_b)
{
    const int nblk = blockIdx.x;
    const int bh = blockIdx.y;
    const int b = bh >> 2, hg = bh & 3;
    const int tid = threadIdx.x;

    __shared__ float ctx[4096];
    for (int idx = tid; idx < 4096; idx += 256)
        ctx[idx] = ctxg[(size_t)bh * 4096 + idx];
    __syncthreads();

    const int n = nblk * 256 + tid;
    const size_t rowidx = (((size_t)(b * NH + LH + hg)) * SEQ + n) * HD;
    const u16* qrow = qh + rowidx;

    float sumexp = 0.f;
    for (int c = 0; c < 8; c++) {
        uint4 v = *(const uint4*)(qrow + c * 8);
        const u16* u = (const u16*)&v;
        #pragma unroll
        for (int jj = 0; jj < 8; jj++) sumexp += __expf(b2f(u[jj]));
    }
    float inv = 0.125f / sumexp;

    f32x4 out4[16];
    #pragma unroll
    for (int t = 0; t < 16; t++)
        for (int i = 0; i < 4; i++) out4[t][i] = 0.f;

    for (int c = 0; c < 8; c++) {
        uint4 v = *(const uint4*)(qrow + c * 8);
        const u16* u = (const u16*)&v;
        #pragma unroll
        for (int jj = 0; jj < 8; jj++) {
            float pd = __expf(b2f(u[jj])) * inv;
            const f32x4* cr = (const f32x4*)&ctx[(c * 8 + jj) * 64];
            #pragma unroll
            for (int t = 0; t < 16; t++)
                out4[t] += pd * cr[t];
        }
    }

    float* ao = attn_out + rowidx;
    #pragma unroll
    for (int t = 0; t < 16; t++)
        *(f32x4*)(ao + t * 4) = out4[t];

    // bf16 copy in y-layout: 128 B contiguous per thread-row
    u16* ab = attn_b + ((size_t)(b * SEQ + n)) * DIM + (LH + hg) * HD;
    #pragma unroll
    for (int t = 0; t < 8; t++) {
        uint4 o; u16* ou = (u16*)&o;
        #pragma unroll
        for (int j = 0; j < 8; j++) ou[j] = f2b(out4[t * 2 + (j >> 2)][j & 3]);
        *(uint4*)(ab + t * 8) = o;
    }
}

// ---------------------------------------------------------------------------
// Kernel D: y = attn_b @ Wproj^T + bproj. Structurally identical to
// gemm_qk_tiled: both operands via global_load_lds(16B), no in-loop convert.
// ---------------------------------------------------------------------------
__global__ __launch_bounds__(256) void proj_gemm_tiled(const u16* __restrict__ attn_b,
        const u16* __restrict__ Wproj, const float* __restrict__ bproj,
        float* __restrict__ y)
{
    __shared__ __align__(16) u16 smem[8192];   // 16 KB: lA 8 KB + lB 8 KB
    u16* lA = smem;          // [128][32]
    u16* lB = smem + 4096;   // [128][32]

    const int tid = threadIdx.x;
    const int wv = tid >> 6, lane = tid & 63;
    const int quad = lane >> 4, l16 = lane & 15;
    const int wr = wv >> 1, wc = wv & 1;
    const int row0 = blockIdx.y * 128;
    const int col0 = blockIdx.x * 128;
    const int lrow = lane >> 2, lkc = (lane & 3) * 8;

    f32x4 acc[4][4];
    #pragma unroll
    for (int t = 0; t < 4; t++)
        for (int u = 0; u < 4; u++)
            for (int i = 0; i < 4; i++) acc[t][u][i] = 0.f;

    const u16* gA = attn_b + (size_t)(row0 + lrow) * DIM + lkc;
    const u16* gB = Wproj  + (size_t)(col0 + lrow) * DIM + lkc;

    for (int kt = 0; kt < DIM; kt += 32) {
        __syncthreads();
        #pragma unroll
        for (int i = 0; i < 2; i++) {
            int rb = wv * 32 + i * 16;
            gload16(gA + (size_t)rb * DIM + kt, &lA[rb * 32]);
            gload16(gB + (size_t)rb * DIM + kt, &lB[rb * 32]);
        }
        __syncthreads();
        bf16x8 af[4], bfr[4];
        #pragma unroll
        for (int t = 0; t < 4; t++)
            af[t] = *(const bf16x8*)&lA[(wr * 64 + t * 16 + l16) * 32 + quad * 8];
        #pragma unroll
        for (int u = 0; u < 4; u++)
            bfr[u] = *(const bf16x8*)&lB[(wc * 64 + u * 16 + l16) * 32 + quad * 8];
        #pragma unroll
        for (int t = 0; t < 4; t++)
            #pragma unroll
            for (int u = 0; u < 4; u++)
                acc[t][u] = __builtin_amdgcn_mfma_f32_16x16x32_bf16(af[t], bfr[u], acc[t][u], 0, 0, 0);
    }

    #pragma unroll
    for (int u = 0; u < 4; u++) {
        int col = col0 + wc * 64 + u * 16 + l16;
        float bias = bproj[col];
        #pragma unroll
        for (int t = 0; t < 4; t++)
            #pragma unroll
            for (int r = 0; r < 4; r++) {
                int m = row0 + wr * 64 + t * 16 + quad * 4 + r;
                y[(size_t)m * DIM + col] = acc[t][u][r] + bias;
            }
    }
}

// ---------------------------------------------------------------------------
extern "C" void kernel_launch(void* const* d_in, const int* in_sizes, int n_in,
                              void* d_out, int out_size, void* d_ws, size_t ws_size,
                              hipStream_t stream)
{
    (void)in_sizes; (void)n_in; (void)out_size; (void)ws_size;
    const float* x     = (const float*)d_in[0];
    const float* Wq    = (const float*)d_in[1];
    const float* Wkv   = (const float*)d_in[2];
    const float* Wproj = (const float*)d_in[3];
    const float* bproj = (const float*)d_in[4];

    float* y        = (float*)d_out;                         // (B,N,C) fp32
    float* attn_out = y + (size_t)BATCH * SEQ * DIM;         // (B,H,N,64) fp32

    // bf16 x and q staged in the y byte-region (consumed before proj writes y)
    u16* xb = (u16*)y;                                       // 33.5 MB
    u16* qh = xb + (size_t)BATCH * SEQ * DIM;                // 33.5 MB

    // partials scratch: batch-0 global-head slice of attn_out (8,388,608 B).
    // Dead until global_out overwrites it (after reduce_ctx consumed it).
    float* partials = attn_out + (size_t)LH * SEQ * HD;

    char* ws = (char*)d_ws;
    float* S       = (float*)ws;                             // 262144 B (final ctx)
    float* colsum  = (float*)(ws + 262144);                  // 4096 B
    u16*   Wqk     = (u16*)(ws + 266240);                    // 1024x512 bf16 = 1 MB
    u16*   Wproj_b = (u16*)(ws + 266240 + 1048576);          // 512 KB
    u16*   kh      = (u16*)(ws + 266240 + 1048576 + 524288); // 33.5 MB
    u16*   attn_b  = kh + (size_t)BATCH * SEQ * DIM;         // 33.5 MB (ws ~69 MB total)

    const long NX = (long)BATCH * SEQ * DIM;   // 16,777,216

    hipMemsetAsync(colsum, 0, 4096, stream);
    convert_bf16<<<4096, 256, 0, stream>>>(x, xb, NX);
    convert_w3<<<dim3(128, 3), 256, 0, stream>>>(Wq, Wkv, Wproj, Wqk, Wproj_b);

    gemm_qk_tiled<<<dim3(8, 256), 256, 0, stream>>>(xb, Wqk, qh, kh);
    local_attn<<<dim3(NWIN, 16), 256, 0, stream>>>(qh, kh, attn_out, attn_b);
    ctx_accum<<<dim3(32, 16), 256, 0, stream>>>(kh, partials, colsum);
    reduce_ctx<<<dim3(4, 16), 256, 0, stream>>>(partials, colsum, S);
    global_out<<<dim3(32, 16), 256, 0, stream>>>(qh, S, attn_out, attn_b);
    proj_gemm_tiled<<<dim3(4, 256), 256, 0, stream>>>(attn_b, Wproj_b, bproj, y);
}

// Round 6
// 345.232 us; speedup vs baseline: 1.4003x; 1.0666x over previous
//
#include <hip/hip_runtime.h>

#define DIM 512
#define NH 8
#define HD 64
#define LH 4
#define WIN 64
#define BATCH 4
#define SEQ 8192
#define NWIN (SEQ/WIN)   // 128

typedef unsigned short u16;
typedef __bf16 bf16x8 __attribute__((ext_vector_type(8)));
typedef float f32x4 __attribute__((ext_vector_type(4)));

__device__ __forceinline__ float b2f(u16 u) {
    return __uint_as_float(((unsigned int)u) << 16);
}
__device__ __forceinline__ u16 f2b(float f) {
    unsigned int x = __float_as_uint(f);
    return (u16)((x + 0x7FFFu + ((x >> 16) & 1u)) >> 16);
}

// async global->LDS, 16B per lane, lands at ldsbase + lane*16
__device__ __forceinline__ void gload16(const void* g, void* l) {
    __builtin_amdgcn_global_load_lds(
        (__attribute__((address_space(1))) void*)g,
        (__attribute__((address_space(3))) void*)l, 16, 0, 0);
}

// fp32 -> bf16 conversion (x)
__global__ void convert_bf16(const float* __restrict__ src, u16* __restrict__ dst, long n)
{
    long i = ((long)blockIdx.x * 256 + threadIdx.x) * 8;
    const long stride = (long)gridDim.x * 256 * 8;
    for (; i < n; i += stride) {
        uint4 a = *(const uint4*)(src + i), b = *(const uint4*)(src + i + 4);
        const float* af = (const float*)&a;
        const float* bf_ = (const float*)&b;
        uint4 o; u16* ou = (u16*)&o;
        #pragma unroll
        for (int j = 0; j < 4; j++) { ou[j] = f2b(af[j]); ou[4 + j] = f2b(bf_[j]); }
        *(uint4*)(dst + i) = o;
    }
}

// all three weight matrices in one launch: grid.y = slice
__global__ void convert_w3(const float* __restrict__ Wq, const float* __restrict__ Wkv,
                           const float* __restrict__ Wp, u16* __restrict__ Wqk,
                           u16* __restrict__ Wproj_b)
{
    const int slice = blockIdx.y;
    const float* src = (slice == 0) ? Wq : (slice == 1) ? Wkv : Wp;
    u16* dst = (slice == 0) ? Wqk : (slice == 1) ? (Wqk + DIM * DIM) : Wproj_b;
    long i = ((long)blockIdx.x * 256 + threadIdx.x) * 8;
    if (i >= (long)DIM * DIM) return;
    uint4 a = *(const uint4*)(src + i), b = *(const uint4*)(src + i + 4);
    const float* af = (const float*)&a;
    const float* bf_ = (const float*)&b;
    uint4 o; u16* ou = (u16*)&o;
    #pragma unroll
    for (int j = 0; j < 4; j++) { ou[j] = f2b(af[j]); ou[4 + j] = f2b(bf_[j]); }
    *(uint4*)(dst + i) = o;
}

// ---------------------------------------------------------------------------
// Kernel A: [q|k] = x @ [Wq|Wkv]^T, M=32768 x N=1024 x K=512.
// BK=64 (half the barrier drains of BK=32) + XOR slot-swizzle:
// LDS rows are 128 B (64 bf16, 8 x 16B slots); logical slot c of row r is
// stored at physical slot c^(r&7). gload16 writes linearly, so the per-lane
// GLOBAL source is pre-swizzled (rule: swizzle both sides or neither).
// ---------------------------------------------------------------------------
__global__ __launch_bounds__(256) void gemm_qk_tiled(const u16* __restrict__ xb,
        const u16* __restrict__ Wqk, u16* __restrict__ qh, u16* __restrict__ kh)
{
    __shared__ __align__(16) u16 smem[16384];  // 32 KB: lA[128][64] + lB[128][64]; epilogue reuses 32 KB
    u16* lA = smem;           // [128][64] swizzled
    u16* lB = smem + 8192;    // [128][64] swizzled

    const int tid = threadIdx.x;
    const int wv = tid >> 6, lane = tid & 63;
    const int quad = lane >> 4, l16 = lane & 15;
    const int wr = wv >> 1, wc = wv & 1;
    const int row0 = blockIdx.y * 128;
    const int col0 = blockIdx.x * 128;
    // staging: per call a wave covers 8 rows x 8 slots (16B each)
    const int srow = lane >> 3;                  // 0..7 (== r&7, calls are 8-row aligned)
    const int scol = ((lane & 7) ^ srow) * 8;    // pre-swizzled source column

    f32x4 acc[4][4];
    #pragma unroll
    for (int t = 0; t < 4; t++)
        for (int u = 0; u < 4; u++)
            for (int i = 0; i < 4; i++) acc[t][u][i] = 0.f;

    const u16* gA = xb  + (size_t)(row0 + srow) * DIM + scol;
    const u16* gB = Wqk + (size_t)(col0 + srow) * DIM + scol;

    for (int kt = 0; kt < DIM; kt += 64) {
        __syncthreads();
        #pragma unroll
        for (int i = 0; i < 4; i++) {
            int rb = wv * 32 + i * 8;
            gload16(gA + (size_t)rb * DIM + kt, &lA[rb * 64]);
            gload16(gB + (size_t)rb * DIM + kt, &lB[rb * 64]);
        }
        __syncthreads();
        #pragma unroll
        for (int kc = 0; kc < 2; kc++) {
            bf16x8 af[4], bfr[4];
            #pragma unroll
            for (int t = 0; t < 4; t++) {
                int row = wr * 64 + t * 16 + l16;
                int slot = (kc * 4 + quad) ^ (row & 7);
                af[t] = *(const bf16x8*)&lA[row * 64 + slot * 8];
            }
            #pragma unroll
            for (int u = 0; u < 4; u++) {
                int row = wc * 64 + u * 16 + l16;
                int slot = (kc * 4 + quad) ^ (row & 7);
                bfr[u] = *(const bf16x8*)&lB[row * 64 + slot * 8];
            }
            #pragma unroll
            for (int t = 0; t < 4; t++)
                #pragma unroll
                for (int u = 0; u < 4; u++)
                    acc[t][u] = __builtin_amdgcn_mfma_f32_16x16x32_bf16(af[t], bfr[u], acc[t][u], 0, 0, 0);
        }
    }

    // epilogue: wave-local 64x64 bf16 C-tile in LDS, then coalesced stores
    __syncthreads();
    u16* cw = smem + wv * 4096;
    #pragma unroll
    for (int t = 0; t < 4; t++)
        #pragma unroll
        for (int u = 0; u < 4; u++)
            #pragma unroll
            for (int r = 0; r < 4; r++)
                cw[(t * 16 + quad * 4 + r) * 64 + u * 16 + l16] = f2b(acc[t][u][r]);

    const int colg0 = col0 + wc * 64;            // wave's 64 cols = one full head
    const int seg = lane & 7;
    u16* dstbase;
    {
        int h = (colg0 & 511) >> 6;
        u16* base = (colg0 < 512) ? qh : kh;
        dstbase = base + (size_t)h * SEQ * HD;   // + b*NH*SEQ*HD later
    }
    #pragma unroll
    for (int i = 0; i < 8; i++) {
        int mm = i * 8 + (lane >> 3);
        uint4 v = *(const uint4*)&cw[mm * 64 + seg * 8];
        int m = row0 + wr * 64 + mm;
        int bb = m >> 13, nn = m & (SEQ - 1);
        *(uint4*)(dstbase + ((size_t)bb * NH * SEQ + nn) * HD + seg * 8) = v;
    }
}

// ---------------------------------------------------------------------------
// Kernel B: local attention (unchanged). Emits fp32 attn + bf16 attn_b.
// ---------------------------------------------------------------------------
#define KJ_STRIDE 72
#define KT_STRIDE 200
#define OT_STRIDE 80   // bf16 o-tile stride: 160 B rows keep uint4 alignment

__global__ __launch_bounds__(256) void local_attn(const u16* __restrict__ qh,
        const u16* __restrict__ kh, float* __restrict__ attn_out,
        u16* __restrict__ attn_b)
{
    __shared__ __align__(16) u16 kjP[192 * KJ_STRIDE];
    __shared__ __align__(16) u16 kT[64 * KT_STRIDE];

    const int w = blockIdx.x;
    const int bh = blockIdx.y;
    const int b = bh >> 2, h = bh & 3;
    const int tid = threadIdx.x;
    const int wv = tid >> 6, lane = tid & 63;
    const int quad = lane >> 4, l16 = lane & 15;

    for (int idx = tid; idx < 192 * 8; idx += 256) {
        int j = idx >> 3, dc = (idx & 7) << 3;
        int n = w * WIN - WIN + j;
        uint4 val = make_uint4(0, 0, 0, 0);
        if (n >= 0 && n < SEQ)
            val = *(const uint4*)(kh + (((size_t)(b * NH + h)) * SEQ + n) * HD + dc);
        *(uint4*)(&kjP[j * KJ_STRIDE + dc]) = val;
    }
    __syncthreads();
    for (int idx = tid; idx < 64 * 192; idx += 256) {
        int e = idx & 63, j = idx >> 6;
        kT[e * KT_STRIDE + j] = kjP[j * KJ_STRIDE + e];
    }
    __syncthreads();

    f32x4 s[12];
    #pragma unroll
    for (int t = 0; t < 12; t++)
        for (int i = 0; i < 4; i++) s[t][i] = 0.f;

    const u16* qrow = qh + (((size_t)(b * NH + h)) * SEQ + w * WIN + wv * 16 + l16) * HD + quad * 8;
    #pragma unroll
    for (int kk = 0; kk < 64; kk += 32) {
        bf16x8 a = *(const bf16x8*)(qrow + kk);
        #pragma unroll
        for (int t = 0; t < 12; t++) {
            bf16x8 bf = *(const bf16x8*)(&kjP[(t * 16 + l16) * KJ_STRIDE + kk + quad * 8]);
            s[t] = __builtin_amdgcn_mfma_f32_16x16x32_bf16(a, bf, s[t], 0, 0, 0);
        }
    }
    __syncthreads();

    const float scale = 0.125f;
    #pragma unroll
    for (int r = 0; r < 4; r++) {
        float vals[12];
        float mx = -3.0e38f;
        #pragma unroll
        for (int t = 0; t < 12; t++) {
            int j = t * 16 + l16;
            float v = s[t][r] * scale;
            bool valid = !((w == 0 && j < 64) || (w == NWIN - 1 && j >= 128));
            v = valid ? v : -30000.0f;
            vals[t] = v;
            mx = fmaxf(mx, v);
        }
        for (int m = 1; m <= 8; m <<= 1) mx = fmaxf(mx, __shfl_xor(mx, m));
        float sum = 0.f;
        #pragma unroll
        for (int t = 0; t < 12; t++) { vals[t] = __expf(vals[t] - mx); sum += vals[t]; }
        for (int m = 1; m <= 8; m <<= 1) sum += __shfl_xor(sum, m);
        float inv = 1.0f / sum;
        int prow = wv * 16 + quad * 4 + r;
        #pragma unroll
        for (int t = 0; t < 12; t++)
            kjP[prow * KT_STRIDE + t * 16 + l16] = f2b(vals[t] * inv);
    }
    __syncthreads();

    f32x4 o[4];
    #pragma unroll
    for (int t = 0; t < 4; t++)
        for (int i = 0; i < 4; i++) o[t][i] = 0.f;
    #pragma unroll
    for (int kc = 0; kc < 6; kc++) {
        bf16x8 a = *(const bf16x8*)(&kjP[(wv * 16 + l16) * KT_STRIDE + kc * 32 + quad * 8]);
        #pragma unroll
        for (int t = 0; t < 4; t++) {
            bf16x8 bf = *(const bf16x8*)(&kT[(t * 16 + l16) * KT_STRIDE + kc * 32 + quad * 8]);
            o[t] = __builtin_amdgcn_mfma_f32_16x16x32_bf16(a, bf, o[t], 0, 0, 0);
        }
    }
    // fp32 attn output (required result tensor)
    #pragma unroll
    for (int t = 0; t < 4; t++) {
        int e = t * 16 + l16;
        #pragma unroll
        for (int r = 0; r < 4; r++) {
            int n = w * WIN + wv * 16 + quad * 4 + r;
            attn_out[(((size_t)(b * NH + h)) * SEQ + n) * HD + e] = o[t][r];
        }
    }
    // bf16 copy in y-layout for proj GEMM: stage 64x64 tile in kT (now free)
    __syncthreads();
    #pragma unroll
    for (int t = 0; t < 4; t++)
        #pragma unroll
        for (int r = 0; r < 4; r++)
            kT[(wv * 16 + quad * 4 + r) * OT_STRIDE + t * 16 + l16] = f2b(o[t][r]);
    __syncthreads();
    for (int idx = tid; idx < 512; idx += 256) {
        int row = idx >> 3, seg = (idx & 7) * 8;
        uint4 v = *(const uint4*)&kT[row * OT_STRIDE + seg];
        *(uint4*)(attn_b + ((size_t)(b * SEQ + w * WIN + row)) * DIM + h * HD + seg) = v;
    }
}

// ---------------------------------------------------------------------------
// Kernel C1: linear attention context accumulate (unchanged from R2).
// ---------------------------------------------------------------------------
__global__ __launch_bounds__(256) void ctx_accum(const u16* __restrict__ kh,
        float* __restrict__ partials, float* __restrict__ colsum)
{
    const int chunk = blockIdx.x;          // 32 chunks x 256 rows
    const int bh = blockIdx.y;
    const int b = bh >> 2, hg = bh & 3;
    const int tid = threadIdx.x;
    const int wv = tid >> 6, lane = tid & 63;
    const int d0 = (lane >> 2) * 4;        // 16 d-groups of 4
    const int e0 = (lane & 3) * 16;        // 4 e-groups of 16

    __shared__ __align__(16) float smem[2 * 64 * 68];   // 34,816 B
    float* kraw = smem;
    float* kexp = smem + 64 * 68;

    f32x4 acc[4][4];
    #pragma unroll
    for (int dd = 0; dd < 4; dd++)
        #pragma unroll
        for (int j = 0; j < 4; j++)
            for (int i = 0; i < 4; i++) acc[dd][j][i] = 0.f;
    f32x4 csum;
    for (int i = 0; i < 4; i++) csum[i] = 0.f;

    const u16* kbase = kh + ((size_t)(b * NH + LH + hg)) * SEQ * HD
                          + (size_t)chunk * 256 * HD;

    for (int ph = 0; ph < 4; ph++) {
        __syncthreads();
        #pragma unroll
        for (int pass = 0; pass < 2; pass++) {
            int idx = pass * 256 + tid;
            int row = idx >> 3, seg = (idx & 7) * 8;
            uint4 v = *(const uint4*)(kbase + ((size_t)(ph * 64 + row)) * HD + seg);
            const u16* u = (const u16*)&v;
            f32x4 r0, r1, E0, E1;
            #pragma unroll
            for (int j = 0; j < 4; j++) {
                r0[j] = b2f(u[j]);      E0[j] = __expf(r0[j]);
                r1[j] = b2f(u[4 + j]);  E1[j] = __expf(r1[j]);
            }
            float* kr = &kraw[row * 68 + seg];
            float* ke = &kexp[row * 68 + seg];
            *(f32x4*)kr = r0;  *(f32x4*)(kr + 4) = r1;
            *(f32x4*)ke = E0;  *(f32x4*)(ke + 4) = E1;
        }
        __syncthreads();
        #pragma unroll 4
        for (int i = 0; i < 16; i++) {
            int roff = (wv * 16 + i) * 68;
            f32x4 ek = *(const f32x4*)&kexp[roff + d0];
            const f32x4* kv = (const f32x4*)&kraw[roff + e0];
            f32x4 k0 = kv[0], k1 = kv[1], k2 = kv[2], k3 = kv[3];
            csum += ek;
            #pragma unroll
            for (int dd = 0; dd < 4; dd++) {
                acc[dd][0] += ek[dd] * k0;
                acc[dd][1] += ek[dd] * k1;
                acc[dd][2] += ek[dd] * k2;
                acc[dd][3] += ek[dd] * k3;
            }
        }
    }

    // cross-wave tree reduction (reuse smem)
    float* red0 = smem;          // [4160]
    float* red1 = smem + 4160;   // [4160]
    __syncthreads();
    if (wv >= 2) {
        float* rd = (wv == 2) ? red0 : red1;
        #pragma unroll
        for (int dd = 0; dd < 4; dd++)
            #pragma unroll
            for (int j = 0; j < 4; j++)
                *(f32x4*)&rd[(d0 + dd) * 64 + e0 + j * 4] = acc[dd][j];
        if ((lane & 3) == 0) *(f32x4*)&rd[4096 + d0] = csum;
    }
    __syncthreads();
    if (wv < 2) {
        float* rd = (wv == 0) ? red0 : red1;
        #pragma unroll
        for (int dd = 0; dd < 4; dd++)
            #pragma unroll
            for (int j = 0; j < 4; j++)
                acc[dd][j] += *(const f32x4*)&rd[(d0 + dd) * 64 + e0 + j * 4];
        csum += *(const f32x4*)&rd[4096 + d0];
    }
    __syncthreads();
    if (wv == 1) {
        #pragma unroll
        for (int dd = 0; dd < 4; dd++)
            #pragma unroll
            for (int j = 0; j < 4; j++)
                *(f32x4*)&red0[(d0 + dd) * 64 + e0 + j * 4] = acc[dd][j];
        if ((lane & 3) == 0) *(f32x4*)&red0[4096 + d0] = csum;
    }
    __syncthreads();
    if (wv == 0) {
        float* P = partials + ((size_t)(chunk * 16 + bh)) * 4096;
        #pragma unroll
        for (int dd = 0; dd < 4; dd++)
            #pragma unroll
            for (int j = 0; j < 4; j++) {
                f32x4 r = acc[dd][j] + *(const f32x4*)&red0[(d0 + dd) * 64 + e0 + j * 4];
                *(f32x4*)&P[(d0 + dd) * 64 + e0 + j * 4] = r;
            }
        if ((lane & 3) == 0) {
            f32x4 cs = csum + *(const f32x4*)&red0[4096 + d0];
            #pragma unroll
            for (int dd = 0; dd < 4; dd++)
                atomicAdd(colsum + bh * 64 + d0 + dd, cs[dd]);
        }
    }
}

// ---------------------------------------------------------------------------
// Kernel C1b: fold 32 partials + colsum division -> bf16 ctx^T (e-major),
// the B-operand layout for global_out's MFMA.
// ---------------------------------------------------------------------------
__global__ __launch_bounds__(256) void reduce_ctx(const float* __restrict__ partials,
        const float* __restrict__ colsum, u16* __restrict__ ctxT)
{
    const int quarter = blockIdx.x;        // 4 x 1024 idx
    const int bh = blockIdx.y;
    const int tid = threadIdx.x;
    __shared__ float cs[64];
    if (tid < 64) cs[tid] = colsum[bh * 64 + tid];
    __syncthreads();
    const int i0 = quarter * 1024;
    for (int idx = i0 + tid; idx < i0 + 1024; idx += 256) {
        float s = 0.f;
        #pragma unroll 8
        for (int c = 0; c < 32; c++)
            s += partials[((size_t)(c * 16 + bh)) * 4096 + idx];
        int d = idx >> 6, e = idx & 63;
        ctxT[(size_t)bh * 4096 + e * 64 + d] = f2b(s / cs[d]);
    }
}

// ---------------------------------------------------------------------------
// Kernel C2: linear attention output via MFMA. O = P * ctx, K=64.
// P built in-register: exp(q)/rowsum as A-fragments (row=l16, k=quad*8).
// ctx^T bf16 staged in LDS (XOR slot-swizzle, pre-swizzled gload16 source)
// read as B-fragments (col=l16, k=quad*8).
// ---------------------------------------------------------------------------
__global__ __launch_bounds__(256) void global_out(const u16* __restrict__ qh,
        const u16* __restrict__ ctxT, float* __restrict__ attn_out,
        u16* __restrict__ attn_b)
{
    const int nblk = blockIdx.x;           // 128 blocks x 64 rows
    const int bh = blockIdx.y;
    const int b = bh >> 2, hg = bh & 3;
    const int tid = threadIdx.x;
    const int wv = tid >> 6, lane = tid & 63;
    const int quad = lane >> 4, l16 = lane & 15;

    __shared__ __align__(16) u16 ctxL[64 * 64];   // 8 KB, swizzled [e][d]
    __shared__ __align__(16) u16 ot[64 * OT_STRIDE];

    // stage ctx^T via gload16 (pre-swizzled source), overlaps with q/exp below
    {
        const int srow = lane >> 3;
        const int scol = ((lane & 7) ^ srow) * 8;
        const u16* src = ctxT + (size_t)bh * 4096 + (size_t)srow * 64 + scol;
        #pragma unroll
        for (int j = 0; j < 2; j++) {
            int rb = j * 32 + wv * 8;
            gload16(src + rb * 64, &ctxL[rb * 64]);
        }
    }

    const int n0 = nblk * 64;
    const u16* qp = qh + (((size_t)(b * NH + LH + hg)) * SEQ + n0 + wv * 16 + l16) * HD + quad * 8;
    uint4 v0 = *(const uint4*)(qp);
    uint4 v1 = *(const uint4*)(qp + 32);
    const u16* u0 = (const u16*)&v0;
    const u16* u1 = (const u16*)&v1;
    float e0[8], e1[8];
    float s = 0.f;
    #pragma unroll
    for (int j = 0; j < 8; j++) { e0[j] = __expf(b2f(u0[j])); s += e0[j]; }
    #pragma unroll
    for (int j = 0; j < 8; j++) { e1[j] = __expf(b2f(u1[j])); s += e1[j]; }
    s += __shfl_xor(s, 16);
    s += __shfl_xor(s, 32);                 // row-sum across the 4 lanes of the quad-group
    const float inv = 0.125f / s;
    uint4 p0u, p1u;
    u16* p0 = (u16*)&p0u; u16* p1 = (u16*)&p1u;
    #pragma unroll
    for (int j = 0; j < 8; j++) { p0[j] = f2b(e0[j] * inv); p1[j] = f2b(e1[j] * inv); }
    bf16x8 pa0 = *(const bf16x8*)&p0u;
    bf16x8 pa1 = *(const bf16x8*)&p1u;

    __syncthreads();                        // ctxL ready

    f32x4 acc[4];
    #pragma unroll
    for (int u = 0; u < 4; u++)
        for (int i = 0; i < 4; i++) acc[u][i] = 0.f;
    #pragma unroll
    for (int u = 0; u < 4; u++) {
        int row = u * 16 + l16;
        int s0 = (0 + quad) ^ (row & 7);
        int s1 = (4 + quad) ^ (row & 7);
        bf16x8 b0 = *(const bf16x8*)&ctxL[row * 64 + s0 * 8];
        bf16x8 b1 = *(const bf16x8*)&ctxL[row * 64 + s1 * 8];
        acc[u] = __builtin_amdgcn_mfma_f32_16x16x32_bf16(pa0, b0, acc[u], 0, 0, 0);
        acc[u] = __builtin_amdgcn_mfma_f32_16x16x32_bf16(pa1, b1, acc[u], 0, 0, 0);
    }

    // fp32 attn_out: C layout col=l16, row=quad*4+r
    const size_t obase = ((size_t)(b * NH + LH + hg)) * SEQ + n0 + wv * 16;
    #pragma unroll
    for (int u = 0; u < 4; u++) {
        int ee = u * 16 + l16;
        #pragma unroll
        for (int r = 0; r < 4; r++)
            attn_out[(obase + quad * 4 + r) * HD + ee] = acc[u][r];
    }

    // bf16 copy in y-layout through LDS for coalescing
    #pragma unroll
    for (int u = 0; u < 4; u++)
        #pragma unroll
        for (int r = 0; r < 4; r++)
            ot[(wv * 16 + quad * 4 + r) * OT_STRIDE + u * 16 + l16] = f2b(acc[u][r]);
    __syncthreads();
    for (int idx = tid; idx < 512; idx += 256) {
        int row = idx >> 3, seg = (idx & 7) * 8;
        uint4 vv = *(const uint4*)&ot[row * OT_STRIDE + seg];
        *(uint4*)(attn_b + ((size_t)(b * SEQ + n0 + row)) * DIM + (LH + hg) * HD + seg) = vv;
    }
}

// ---------------------------------------------------------------------------
// Kernel D: y = attn_b @ Wproj^T + bproj. BK=64 + XOR swizzle (same as A).
// ---------------------------------------------------------------------------
__global__ __launch_bounds__(256) void proj_gemm_tiled(const u16* __restrict__ attn_b,
        const u16* __restrict__ Wproj, const float* __restrict__ bproj,
        float* __restrict__ y)
{
    __shared__ __align__(16) u16 smem[16384];   // 32 KB
    u16* lA = smem;           // [128][64]
    u16* lB = smem + 8192;    // [128][64]

    const int tid = threadIdx.x;
    const int wv = tid >> 6, lane = tid & 63;
    const int quad = lane >> 4, l16 = lane & 15;
    const int wr = wv >> 1, wc = wv & 1;
    const int row0 = blockIdx.y * 128;
    const int col0 = blockIdx.x * 128;
    const int srow = lane >> 3;
    const int scol = ((lane & 7) ^ srow) * 8;

    f32x4 acc[4][4];
    #pragma unroll
    for (int t = 0; t < 4; t++)
        for (int u = 0; u < 4; u++)
            for (int i = 0; i < 4; i++) acc[t][u][i] = 0.f;

    const u16* gA = attn_b + (size_t)(row0 + srow) * DIM + scol;
    const u16* gB = Wproj  + (size_t)(col0 + srow) * DIM + scol;

    for (int kt = 0; kt < DIM; kt += 64) {
        __syncthreads();
        #pragma unroll
        for (int i = 0; i < 4; i++) {
            int rb = wv * 32 + i * 8;
            gload16(gA + (size_t)rb * DIM + kt, &lA[rb * 64]);
            gload16(gB + (size_t)rb * DIM + kt, &lB[rb * 64]);
        }
        __syncthreads();
        #pragma unroll
        for (int kc = 0; kc < 2; kc++) {
            bf16x8 af[4], bfr[4];
            #pragma unroll
            for (int t = 0; t < 4; t++) {
                int row = wr * 64 + t * 16 + l16;
                int slot = (kc * 4 + quad) ^ (row & 7);
                af[t] = *(const bf16x8*)&lA[row * 64 + slot * 8];
            }
            #pragma unroll
            for (int u = 0; u < 4; u++) {
                int row = wc * 64 + u * 16 + l16;
                int slot = (kc * 4 + quad) ^ (row & 7);
                bfr[u] = *(const bf16x8*)&lB[row * 64 + slot * 8];
            }
            #pragma unroll
            for (int t = 0; t < 4; t++)
                #pragma unroll
                for (int u = 0; u < 4; u++)
                    acc[t][u] = __builtin_amdgcn_mfma_f32_16x16x32_bf16(af[t], bfr[u], acc[t][u], 0, 0, 0);
        }
    }

    #pragma unroll
    for (int u = 0; u < 4; u++) {
        int col = col0 + wc * 64 + u * 16 + l16;
        float bias = bproj[col];
        #pragma unroll
        for (int t = 0; t < 4; t++)
            #pragma unroll
            for (int r = 0; r < 4; r++) {
                int m = row0 + wr * 64 + t * 16 + quad * 4 + r;
                y[(size_t)m * DIM + col] = acc[t][u][r] + bias;
            }
    }
}

// ---------------------------------------------------------------------------
extern "C" void kernel_launch(void* const* d_in, const int* in_sizes, int n_in,
                              void* d_out, int out_size, void* d_ws, size_t ws_size,
                              hipStream_t stream)
{
    (void)in_sizes; (void)n_in; (void)out_size; (void)ws_size;
    const float* x     = (const float*)d_in[0];
    const float* Wq    = (const float*)d_in[1];
    const float* Wkv   = (const float*)d_in[2];
    const float* Wproj = (const float*)d_in[3];
    const float* bproj = (const float*)d_in[4];

    float* y        = (float*)d_out;                         // (B,N,C) fp32
    float* attn_out = y + (size_t)BATCH * SEQ * DIM;         // (B,H,N,64) fp32

    // bf16 x and q staged in the y byte-region (consumed before proj writes y)
    u16* xb = (u16*)y;                                       // 33.5 MB
    u16* qh = xb + (size_t)BATCH * SEQ * DIM;                // 33.5 MB

    // partials scratch: batch-0 global-head slice of attn_out (8,388,608 B).
    // Dead until global_out overwrites it (after reduce_ctx consumed it).
    float* partials = attn_out + (size_t)LH * SEQ * HD;

    char* ws = (char*)d_ws;
    u16*   ctxT    = (u16*)ws;                               // 16 x 4096 bf16 = 131072 B
    float* colsum  = (float*)(ws + 262144);                  // 4096 B
    u16*   Wqk     = (u16*)(ws + 266240);                    // 1024x512 bf16 = 1 MB
    u16*   Wproj_b = (u16*)(ws + 266240 + 1048576);          // 512 KB
    u16*   kh      = (u16*)(ws + 266240 + 1048576 + 524288); // 33.5 MB
    u16*   attn_b  = kh + (size_t)BATCH * SEQ * DIM;         // 33.5 MB (ws ~69 MB total)

    const long NX = (long)BATCH * SEQ * DIM;   // 16,777,216

    hipMemsetAsync(colsum, 0, 4096, stream);
    convert_bf16<<<4096, 256, 0, stream>>>(x, xb, NX);
    convert_w3<<<dim3(128, 3), 256, 0, stream>>>(Wq, Wkv, Wproj, Wqk, Wproj_b);

    gemm_qk_tiled<<<dim3(8, 256), 256, 0, stream>>>(xb, Wqk, qh, kh);
    local_attn<<<dim3(NWIN, 16), 256, 0, stream>>>(qh, kh, attn_out, attn_b);
    ctx_accum<<<dim3(32, 16), 256, 0, stream>>>(kh, partials, colsum);
    reduce_ctx<<<dim3(4, 16), 256, 0, stream>>>(partials, colsum, ctxT);
    global_out<<<dim3(SEQ / 64, 16), 256, 0, stream>>>(qh, ctxT, attn_out, attn_b);
    proj_gemm_tiled<<<dim3(4, 256), 256, 0, stream>>>(attn_b, Wproj_b, bproj, y);
}

// Round 7
// 341.074 us; speedup vs baseline: 1.4174x; 1.0122x over previous
//
#include <hip/hip_runtime.h>

#define DIM 512
#define NH 8
#define HD 64
#define LH 4
#define WIN 64
#define BATCH 4
#define SEQ 8192
#define NWIN (SEQ/WIN)   // 128

typedef unsigned short u16;
typedef __bf16 bf16x8 __attribute__((ext_vector_type(8)));
typedef float f32x4 __attribute__((ext_vector_type(4)));

__device__ __forceinline__ float b2f(u16 u) {
    return __uint_as_float(((unsigned int)u) << 16);
}
__device__ __forceinline__ u16 f2b(float f) {
    unsigned int x = __float_as_uint(f);
    return (u16)((x + 0x7FFFu + ((x >> 16) & 1u)) >> 16);
}

// async global->LDS, 16B per lane, lands at ldsbase + lane*16
__device__ __forceinline__ void gload16(const void* g, void* l) {
    __builtin_amdgcn_global_load_lds(
        (__attribute__((address_space(1))) void*)g,
        (__attribute__((address_space(3))) void*)l, 16, 0, 0);
}

// fp32 -> bf16 conversion (x)
__global__ void convert_bf16(const float* __restrict__ src, u16* __restrict__ dst, long n)
{
    long i = ((long)blockIdx.x * 256 + threadIdx.x) * 8;
    const long stride = (long)gridDim.x * 256 * 8;
    for (; i < n; i += stride) {
        uint4 a = *(const uint4*)(src + i), b = *(const uint4*)(src + i + 4);
        const float* af = (const float*)&a;
        const float* bf_ = (const float*)&b;
        uint4 o; u16* ou = (u16*)&o;
        #pragma unroll
        for (int j = 0; j < 4; j++) { ou[j] = f2b(af[j]); ou[4 + j] = f2b(bf_[j]); }
        *(uint4*)(dst + i) = o;
    }
}

// all three weight matrices in one launch: grid.y = slice
__global__ void convert_w3(const float* __restrict__ Wq, const float* __restrict__ Wkv,
                           const float* __restrict__ Wp, u16* __restrict__ Wqk,
                           u16* __restrict__ Wproj_b)
{
    const int slice = blockIdx.y;
    const float* src = (slice == 0) ? Wq : (slice == 1) ? Wkv : Wp;
    u16* dst = (slice == 0) ? Wqk : (slice == 1) ? (Wqk + DIM * DIM) : Wproj_b;
    long i = ((long)blockIdx.x * 256 + threadIdx.x) * 8;
    if (i >= (long)DIM * DIM) return;
    uint4 a = *(const uint4*)(src + i), b = *(const uint4*)(src + i + 4);
    const float* af = (const float*)&a;
    const float* bf_ = (const float*)&b;
    uint4 o; u16* ou = (u16*)&o;
    #pragma unroll
    for (int j = 0; j < 4; j++) { ou[j] = f2b(af[j]); ou[4 + j] = f2b(bf_[j]); }
    *(uint4*)(dst + i) = o;
}

// ---------------------------------------------------------------------------
// Kernel A: [q|k] = x @ [Wq|Wkv]^T, M=32768 x N=1024 x K=512.
// BK=64 + XOR slot-swizzle (R6). NEW: for global-head k-tiles (colg0>=768)
// the epilogue also emits the TRANSPOSED tile into khTg[(b*4+hg)][e][n] —
// feeds ctx_accum's MFMA (needs n along the MFMA k-axis).
// ---------------------------------------------------------------------------
__global__ __launch_bounds__(256) void gemm_qk_tiled(const u16* __restrict__ xb,
        const u16* __restrict__ Wqk, u16* __restrict__ qh, u16* __restrict__ kh,
        u16* __restrict__ khTg)
{
    __shared__ __align__(16) u16 smem[16384];  // 32 KB
    u16* lA = smem;           // [128][64] swizzled
    u16* lB = smem + 8192;    // [128][64] swizzled

    const int tid = threadIdx.x;
    const int wv = tid >> 6, lane = tid & 63;
    const int quad = lane >> 4, l16 = lane & 15;
    const int wr = wv >> 1, wc = wv & 1;
    const int row0 = blockIdx.y * 128;
    const int col0 = blockIdx.x * 128;
    const int srow = lane >> 3;                  // 0..7
    const int scol = ((lane & 7) ^ srow) * 8;    // pre-swizzled source column

    f32x4 acc[4][4];
    #pragma unroll
    for (int t = 0; t < 4; t++)
        for (int u = 0; u < 4; u++)
            for (int i = 0; i < 4; i++) acc[t][u][i] = 0.f;

    const u16* gA = xb  + (size_t)(row0 + srow) * DIM + scol;
    const u16* gB = Wqk + (size_t)(col0 + srow) * DIM + scol;

    for (int kt = 0; kt < DIM; kt += 64) {
        __syncthreads();
        #pragma unroll
        for (int i = 0; i < 4; i++) {
            int rb = wv * 32 + i * 8;
            gload16(gA + (size_t)rb * DIM + kt, &lA[rb * 64]);
            gload16(gB + (size_t)rb * DIM + kt, &lB[rb * 64]);
        }
        __syncthreads();
        #pragma unroll
        for (int kc = 0; kc < 2; kc++) {
            bf16x8 af[4], bfr[4];
            #pragma unroll
            for (int t = 0; t < 4; t++) {
                int row = wr * 64 + t * 16 + l16;
                int slot = (kc * 4 + quad) ^ (row & 7);
                af[t] = *(const bf16x8*)&lA[row * 64 + slot * 8];
            }
            #pragma unroll
            for (int u = 0; u < 4; u++) {
                int row = wc * 64 + u * 16 + l16;
                int slot = (kc * 4 + quad) ^ (row & 7);
                bfr[u] = *(const bf16x8*)&lB[row * 64 + slot * 8];
            }
            #pragma unroll
            for (int t = 0; t < 4; t++)
                #pragma unroll
                for (int u = 0; u < 4; u++)
                    acc[t][u] = __builtin_amdgcn_mfma_f32_16x16x32_bf16(af[t], bfr[u], acc[t][u], 0, 0, 0);
        }
    }

    // epilogue: wave-local 64x64 bf16 C-tile in LDS, then coalesced stores
    __syncthreads();
    u16* cw = smem + wv * 4096;
    #pragma unroll
    for (int t = 0; t < 4; t++)
        #pragma unroll
        for (int u = 0; u < 4; u++)
            #pragma unroll
            for (int r = 0; r < 4; r++)
                cw[(t * 16 + quad * 4 + r) * 64 + u * 16 + l16] = f2b(acc[t][u][r]);

    const int colg0 = col0 + wc * 64;            // wave's 64 cols = one full head
    const int seg = lane & 7;
    u16* dstbase;
    {
        int h = (colg0 & 511) >> 6;
        u16* base = (colg0 < 512) ? qh : kh;
        dstbase = base + (size_t)h * SEQ * HD;   // + b*NH*SEQ*HD later
    }
    #pragma unroll
    for (int i = 0; i < 8; i++) {
        int mm = i * 8 + (lane >> 3);
        uint4 v = *(const uint4*)&cw[mm * 64 + seg * 8];
        int m = row0 + wr * 64 + mm;
        int bb = m >> 13, nn = m & (SEQ - 1);
        *(uint4*)(dstbase + ((size_t)bb * NH * SEQ + nn) * HD + seg * 8) = v;
    }

    // NEW: transposed k emission for global heads (k-half, h>=4)
    if (colg0 >= 768) {
        int hg = ((colg0 & 511) >> 6) - 4;
        int m0 = row0 + wr * 64;                 // 64-aligned, within one batch
        int bb = m0 >> 13, nn0 = m0 & (SEQ - 1);
        u16* kT = khTg + ((size_t)((bb << 2) + hg) * 64) * SEQ + nn0;
        #pragma unroll
        for (int i = 0; i < 8; i++) {
            int e = i * 8 + (lane >> 3);
            int ns = (lane & 7) * 8;
            uint4 ov; u16* op = (u16*)&ov;
            #pragma unroll
            for (int j = 0; j < 8; j++) op[j] = cw[(ns + j) * 64 + e];
            *(uint4*)(kT + (size_t)e * SEQ + ns) = ov;
        }
    }
}

// ---------------------------------------------------------------------------
// Kernel B: local attention (unchanged). Emits fp32 attn + bf16 attn_b.
// ---------------------------------------------------------------------------
#define KJ_STRIDE 72
#define KT_STRIDE 200
#define OT_STRIDE 80   // bf16 o-tile stride: 160 B rows keep uint4 alignment

__global__ __launch_bounds__(256) void local_attn(const u16* __restrict__ qh,
        const u16* __restrict__ kh, float* __restrict__ attn_out,
        u16* __restrict__ attn_b)
{
    __shared__ __align__(16) u16 kjP[192 * KJ_STRIDE];
    __shared__ __align__(16) u16 kT[64 * KT_STRIDE];

    const int w = blockIdx.x;
    const int bh = blockIdx.y;
    const int b = bh >> 2, h = bh & 3;
    const int tid = threadIdx.x;
    const int wv = tid >> 6, lane = tid & 63;
    const int quad = lane >> 4, l16 = lane & 15;

    for (int idx = tid; idx < 192 * 8; idx += 256) {
        int j = idx >> 3, dc = (idx & 7) << 3;
        int n = w * WIN - WIN + j;
        uint4 val = make_uint4(0, 0, 0, 0);
        if (n >= 0 && n < SEQ)
            val = *(const uint4*)(kh + (((size_t)(b * NH + h)) * SEQ + n) * HD + dc);
        *(uint4*)(&kjP[j * KJ_STRIDE + dc]) = val;
    }
    __syncthreads();
    for (int idx = tid; idx < 64 * 192; idx += 256) {
        int e = idx & 63, j = idx >> 6;
        kT[e * KT_STRIDE + j] = kjP[j * KJ_STRIDE + e];
    }
    __syncthreads();

    f32x4 s[12];
    #pragma unroll
    for (int t = 0; t < 12; t++)
        for (int i = 0; i < 4; i++) s[t][i] = 0.f;

    const u16* qrow = qh + (((size_t)(b * NH + h)) * SEQ + w * WIN + wv * 16 + l16) * HD + quad * 8;
    #pragma unroll
    for (int kk = 0; kk < 64; kk += 32) {
        bf16x8 a = *(const bf16x8*)(qrow + kk);
        #pragma unroll
        for (int t = 0; t < 12; t++) {
            bf16x8 bf = *(const bf16x8*)(&kjP[(t * 16 + l16) * KJ_STRIDE + kk + quad * 8]);
            s[t] = __builtin_amdgcn_mfma_f32_16x16x32_bf16(a, bf, s[t], 0, 0, 0);
        }
    }
    __syncthreads();

    const float scale = 0.125f;
    #pragma unroll
    for (int r = 0; r < 4; r++) {
        float vals[12];
        float mx = -3.0e38f;
        #pragma unroll
        for (int t = 0; t < 12; t++) {
            int j = t * 16 + l16;
            float v = s[t][r] * scale;
            bool valid = !((w == 0 && j < 64) || (w == NWIN - 1 && j >= 128));
            v = valid ? v : -30000.0f;
            vals[t] = v;
            mx = fmaxf(mx, v);
        }
        for (int m = 1; m <= 8; m <<= 1) mx = fmaxf(mx, __shfl_xor(mx, m));
        float sum = 0.f;
        #pragma unroll
        for (int t = 0; t < 12; t++) { vals[t] = __expf(vals[t] - mx); sum += vals[t]; }
        for (int m = 1; m <= 8; m <<= 1) sum += __shfl_xor(sum, m);
        float inv = 1.0f / sum;
        int prow = wv * 16 + quad * 4 + r;
        #pragma unroll
        for (int t = 0; t < 12; t++)
            kjP[prow * KT_STRIDE + t * 16 + l16] = f2b(vals[t] * inv);
    }
    __syncthreads();

    f32x4 o[4];
    #pragma unroll
    for (int t = 0; t < 4; t++)
        for (int i = 0; i < 4; i++) o[t][i] = 0.f;
    #pragma unroll
    for (int kc = 0; kc < 6; kc++) {
        bf16x8 a = *(const bf16x8*)(&kjP[(wv * 16 + l16) * KT_STRIDE + kc * 32 + quad * 8]);
        #pragma unroll
        for (int t = 0; t < 4; t++) {
            bf16x8 bf = *(const bf16x8*)(&kT[(t * 16 + l16) * KT_STRIDE + kc * 32 + quad * 8]);
            o[t] = __builtin_amdgcn_mfma_f32_16x16x32_bf16(a, bf, o[t], 0, 0, 0);
        }
    }
    // fp32 attn output (required result tensor)
    #pragma unroll
    for (int t = 0; t < 4; t++) {
        int e = t * 16 + l16;
        #pragma unroll
        for (int r = 0; r < 4; r++) {
            int n = w * WIN + wv * 16 + quad * 4 + r;
            attn_out[(((size_t)(b * NH + h)) * SEQ + n) * HD + e] = o[t][r];
        }
    }
    // bf16 copy in y-layout for proj GEMM: stage 64x64 tile in kT (now free)
    __syncthreads();
    #pragma unroll
    for (int t = 0; t < 4; t++)
        #pragma unroll
        for (int r = 0; r < 4; r++)
            kT[(wv * 16 + quad * 4 + r) * OT_STRIDE + t * 16 + l16] = f2b(o[t][r]);
    __syncthreads();
    for (int idx = tid; idx < 512; idx += 256) {
        int row = idx >> 3, seg = (idx & 7) * 8;
        uint4 v = *(const uint4*)&kT[row * OT_STRIDE + seg];
        *(uint4*)(attn_b + ((size_t)(b * SEQ + w * WIN + row)) * DIM + h * HD + seg) = v;
    }
}

// ---------------------------------------------------------------------------
// Kernel C1: linear attention context accumulate — MFMA rewrite.
// S[d][e] = sum_n exp(khT[d][n]) * khT[e][n]  — a B^T-convention GEMM with an
// elementwise exp on A. Per block (chunk, bh): 4 tiles of BK=64; B staged raw
// via pre-swizzled gload16, A staged as bf16(exp) via reg path with swizzled
// ds_writes (colsum accumulated from the ROUNDED exp). Wave w computes the
// 16-row d-strip [w*16, w*16+16). Partials layout identical to R6.
// ---------------------------------------------------------------------------
__global__ __launch_bounds__(256) void ctx_accum(const u16* __restrict__ khTg,
        float* __restrict__ partials, float* __restrict__ colsum)
{
    const int chunk = blockIdx.x;          // 32 chunks x 256 n
    const int bh = blockIdx.y;             // global-head index b*4+hg
    const int tid = threadIdx.x;
    const int wv = tid >> 6, lane = tid & 63;
    const int quad = lane >> 4, l16 = lane & 15;

    __shared__ __align__(16) u16 rawL[64 * 64];   // 8 KB [e][n] swizzled
    __shared__ __align__(16) u16 expL[64 * 64];   // 8 KB [d][n] swizzled

    const u16* base = khTg + (size_t)bh * 64 * SEQ;
    const int dexp = tid >> 2;                 // exp-path row (0..63)
    const int nsub = (tid & 3) * 16;           // exp-path n-offset in tile

    const int srow = lane >> 3;
    const int scol = ((lane & 7) ^ srow) * 8;

    f32x4 acc[4];
    #pragma unroll
    for (int u = 0; u < 4; u++)
        for (int i = 0; i < 4; i++) acc[u][i] = 0.f;
    float csum = 0.f;

    for (int t = 0; t < 4; t++) {
        const int n0 = chunk * 256 + t * 64;
        __syncthreads();
        // B: raw khT tile via async direct-to-LDS (pre-swizzled source)
        #pragma unroll
        for (int i = 0; i < 2; i++) {
            int r0 = wv * 16 + i * 8;
            gload16(base + (size_t)(r0 + srow) * SEQ + n0 + scol, &rawL[r0 * 64]);
        }
        // A: exp(khT) in bf16, swizzled ds_writes; csum from rounded values
        {
            const u16* g = base + (size_t)dexp * SEQ + n0 + nsub;
            uint4 v0 = *(const uint4*)g;
            uint4 v1 = *(const uint4*)(g + 8);
            const u16* ua = (const u16*)&v0;
            const u16* ub = (const u16*)&v1;
            uint4 o0, o1; u16* pa = (u16*)&o0; u16* pb = (u16*)&o1;
            #pragma unroll
            for (int j = 0; j < 8; j++) {
                u16 ra = f2b(__expf(b2f(ua[j])));
                u16 rb = f2b(__expf(b2f(ub[j])));
                pa[j] = ra; pb[j] = rb;
                csum += b2f(ra) + b2f(rb);
            }
            int sl0 = ((nsub >> 3) + 0) ^ (dexp & 7);
            int sl1 = ((nsub >> 3) + 1) ^ (dexp & 7);
            *(uint4*)&expL[dexp * 64 + sl0 * 8] = o0;
            *(uint4*)&expL[dexp * 64 + sl1 * 8] = o1;
        }
        __syncthreads();
        // MFMA: wave's d-strip x all e, K=64
        #pragma unroll
        for (int kc = 0; kc < 2; kc++) {
            int arow = wv * 16 + l16;
            bf16x8 af = *(const bf16x8*)&expL[arow * 64 + (((kc * 4 + quad) ^ (arow & 7)) * 8)];
            #pragma unroll
            for (int u = 0; u < 4; u++) {
                int brow = u * 16 + l16;
                bf16x8 bf = *(const bf16x8*)&rawL[brow * 64 + (((kc * 4 + quad) ^ (brow & 7)) * 8)];
                acc[u] = __builtin_amdgcn_mfma_f32_16x16x32_bf16(af, bf, acc[u], 0, 0, 0);
            }
        }
    }

    // partial S write: S[d = wv*16+quad*4+r][e = u*16+l16]
    float* P = partials + ((size_t)(chunk * 16 + bh)) * 4096;
    #pragma unroll
    for (int u = 0; u < 4; u++)
        #pragma unroll
        for (int r = 0; r < 4; r++)
            P[(wv * 16 + quad * 4 + r) * 64 + u * 16 + l16] = acc[u][r];

    // colsum: fold the 4 threads sharing d, one atomic per (block, d)
    csum += __shfl_xor(csum, 1);
    csum += __shfl_xor(csum, 2);
    if ((tid & 3) == 0) atomicAdd(colsum + bh * 64 + dexp, csum);
}

// ---------------------------------------------------------------------------
// Kernel C1b: fold 32 partials + colsum division -> bf16 ctx^T (e-major).
// ---------------------------------------------------------------------------
__global__ __launch_bounds__(256) void reduce_ctx(const float* __restrict__ partials,
        const float* __restrict__ colsum, u16* __restrict__ ctxT)
{
    const int quarter = blockIdx.x;        // 4 x 1024 idx
    const int bh = blockIdx.y;
    const int tid = threadIdx.x;
    __shared__ float cs[64];
    if (tid < 64) cs[tid] = colsum[bh * 64 + tid];
    __syncthreads();
    const int i0 = quarter * 1024;
    for (int idx = i0 + tid; idx < i0 + 1024; idx += 256) {
        float s = 0.f;
        #pragma unroll 8
        for (int c = 0; c < 32; c++)
            s += partials[((size_t)(c * 16 + bh)) * 4096 + idx];
        int d = idx >> 6, e = idx & 63;
        ctxT[(size_t)bh * 4096 + e * 64 + d] = f2b(s / cs[d]);
    }
}

// ---------------------------------------------------------------------------
// Kernel C2: linear attention output via MFMA (unchanged from R6).
// ---------------------------------------------------------------------------
__global__ __launch_bounds__(256) void global_out(const u16* __restrict__ qh,
        const u16* __restrict__ ctxT, float* __restrict__ attn_out,
        u16* __restrict__ attn_b)
{
    const int nblk = blockIdx.x;           // 128 blocks x 64 rows
    const int bh = blockIdx.y;
    const int b = bh >> 2, hg = bh & 3;
    const int tid = threadIdx.x;
    const int wv = tid >> 6, lane = tid & 63;
    const int quad = lane >> 4, l16 = lane & 15;

    __shared__ __align__(16) u16 ctxL[64 * 64];   // 8 KB, swizzled [e][d]
    __shared__ __align__(16) u16 ot[64 * OT_STRIDE];

    // stage ctx^T via gload16 (pre-swizzled source), overlaps with q/exp below
    {
        const int srow = lane >> 3;
        const int scol = ((lane & 7) ^ srow) * 8;
        const u16* src = ctxT + (size_t)bh * 4096 + (size_t)srow * 64 + scol;
        #pragma unroll
        for (int j = 0; j < 2; j++) {
            int rb = j * 32 + wv * 8;
            gload16(src + rb * 64, &ctxL[rb * 64]);
        }
    }

    const int n0 = nblk * 64;
    const u16* qp = qh + (((size_t)(b * NH + LH + hg)) * SEQ + n0 + wv * 16 + l16) * HD + quad * 8;
    uint4 v0 = *(const uint4*)(qp);
    uint4 v1 = *(const uint4*)(qp + 32);
    const u16* u0 = (const u16*)&v0;
    const u16* u1 = (const u16*)&v1;
    float e0[8], e1[8];
    float s = 0.f;
    #pragma unroll
    for (int j = 0; j < 8; j++) { e0[j] = __expf(b2f(u0[j])); s += e0[j]; }
    #pragma unroll
    for (int j = 0; j < 8; j++) { e1[j] = __expf(b2f(u1[j])); s += e1[j]; }
    s += __shfl_xor(s, 16);
    s += __shfl_xor(s, 32);                 // row-sum across the 4 lanes of the quad-group
    const float inv = 0.125f / s;
    uint4 p0u, p1u;
    u16* p0 = (u16*)&p0u; u16* p1 = (u16*)&p1u;
    #pragma unroll
    for (int j = 0; j < 8; j++) { p0[j] = f2b(e0[j] * inv); p1[j] = f2b(e1[j] * inv); }
    bf16x8 pa0 = *(const bf16x8*)&p0u;
    bf16x8 pa1 = *(const bf16x8*)&p1u;

    __syncthreads();                        // ctxL ready

    f32x4 acc[4];
    #pragma unroll
    for (int u = 0; u < 4; u++)
        for (int i = 0; i < 4; i++) acc[u][i] = 0.f;
    #pragma unroll
    for (int u = 0; u < 4; u++) {
        int row = u * 16 + l16;
        int s0 = (0 + quad) ^ (row & 7);
        int s1 = (4 + quad) ^ (row & 7);
        bf16x8 b0 = *(const bf16x8*)&ctxL[row * 64 + s0 * 8];
        bf16x8 b1 = *(const bf16x8*)&ctxL[row * 64 + s1 * 8];
        acc[u] = __builtin_amdgcn_mfma_f32_16x16x32_bf16(pa0, b0, acc[u], 0, 0, 0);
        acc[u] = __builtin_amdgcn_mfma_f32_16x16x32_bf16(pa1, b1, acc[u], 0, 0, 0);
    }

    // fp32 attn_out: C layout col=l16, row=quad*4+r
    const size_t obase = ((size_t)(b * NH + LH + hg)) * SEQ + n0 + wv * 16;
    #pragma unroll
    for (int u = 0; u < 4; u++) {
        int ee = u * 16 + l16;
        #pragma unroll
        for (int r = 0; r < 4; r++)
            attn_out[(obase + quad * 4 + r) * HD + ee] = acc[u][r];
    }

    // bf16 copy in y-layout through LDS for coalescing
    #pragma unroll
    for (int u = 0; u < 4; u++)
        #pragma unroll
        for (int r = 0; r < 4; r++)
            ot[(wv * 16 + quad * 4 + r) * OT_STRIDE + u * 16 + l16] = f2b(acc[u][r]);
    __syncthreads();
    for (int idx = tid; idx < 512; idx += 256) {
        int row = idx >> 3, seg = (idx & 7) * 8;
        uint4 vv = *(const uint4*)&ot[row * OT_STRIDE + seg];
        *(uint4*)(attn_b + ((size_t)(b * SEQ + n0 + row)) * DIM + (LH + hg) * HD + seg) = vv;
    }
}

// ---------------------------------------------------------------------------
// Kernel D: y = attn_b @ Wproj^T + bproj. BK=64 + XOR swizzle (unchanged).
// ---------------------------------------------------------------------------
__global__ __launch_bounds__(256) void proj_gemm_tiled(const u16* __restrict__ attn_b,
        const u16* __restrict__ Wproj, const float* __restrict__ bproj,
        float* __restrict__ y)
{
    __shared__ __align__(16) u16 smem[16384];   // 32 KB
    u16* lA = smem;           // [128][64]
    u16* lB = smem + 8192;    // [128][64]

    const int tid = threadIdx.x;
    const int wv = tid >> 6, lane = tid & 63;
    const int quad = lane >> 4, l16 = lane & 15;
    const int wr = wv >> 1, wc = wv & 1;
    const int row0 = blockIdx.y * 128;
    const int col0 = blockIdx.x * 128;
    const int srow = lane >> 3;
    const int scol = ((lane & 7) ^ srow) * 8;

    f32x4 acc[4][4];
    #pragma unroll
    for (int t = 0; t < 4; t++)
        for (int u = 0; u < 4; u++)
            for (int i = 0; i < 4; i++) acc[t][u][i] = 0.f;

    const u16* gA = attn_b + (size_t)(row0 + srow) * DIM + scol;
    const u16* gB = Wproj  + (size_t)(col0 + srow) * DIM + scol;

    for (int kt = 0; kt < DIM; kt += 64) {
        __syncthreads();
        #pragma unroll
        for (int i = 0; i < 4; i++) {
            int rb = wv * 32 + i * 8;
            gload16(gA + (size_t)rb * DIM + kt, &lA[rb * 64]);
            gload16(gB + (size_t)rb * DIM + kt, &lB[rb * 64]);
        }
        __syncthreads();
        #pragma unroll
        for (int kc = 0; kc < 2; kc++) {
            bf16x8 af[4], bfr[4];
            #pragma unroll
            for (int t = 0; t < 4; t++) {
                int row = wr * 64 + t * 16 + l16;
                int slot = (kc * 4 + quad) ^ (row & 7);
                af[t] = *(const bf16x8*)&lA[row * 64 + slot * 8];
            }
            #pragma unroll
            for (int u = 0; u < 4; u++) {
                int row = wc * 64 + u * 16 + l16;
                int slot = (kc * 4 + quad) ^ (row & 7);
                bfr[u] = *(const bf16x8*)&lB[row * 64 + slot * 8];
            }
            #pragma unroll
            for (int t = 0; t < 4; t++)
                #pragma unroll
                for (int u = 0; u < 4; u++)
                    acc[t][u] = __builtin_amdgcn_mfma_f32_16x16x32_bf16(af[t], bfr[u], acc[t][u], 0, 0, 0);
        }
    }

    #pragma unroll
    for (int u = 0; u < 4; u++) {
        int col = col0 + wc * 64 + u * 16 + l16;
        float bias = bproj[col];
        #pragma unroll
        for (int t = 0; t < 4; t++)
            #pragma unroll
            for (int r = 0; r < 4; r++) {
                int m = row0 + wr * 64 + t * 16 + quad * 4 + r;
                y[(size_t)m * DIM + col] = acc[t][u][r] + bias;
            }
    }
}

// ---------------------------------------------------------------------------
extern "C" void kernel_launch(void* const* d_in, const int* in_sizes, int n_in,
                              void* d_out, int out_size, void* d_ws, size_t ws_size,
                              hipStream_t stream)
{
    (void)in_sizes; (void)n_in; (void)out_size; (void)ws_size;
    const float* x     = (const float*)d_in[0];
    const float* Wq    = (const float*)d_in[1];
    const float* Wkv   = (const float*)d_in[2];
    const float* Wproj = (const float*)d_in[3];
    const float* bproj = (const float*)d_in[4];

    float* y        = (float*)d_out;                         // (B,N,C) fp32
    float* attn_out = y + (size_t)BATCH * SEQ * DIM;         // (B,H,N,64) fp32

    // bf16 x and q staged in the y byte-region (consumed before proj writes y)
    u16* xb = (u16*)y;                                       // 33.5 MB
    u16* qh = xb + (size_t)BATCH * SEQ * DIM;                // 33.5 MB

    // partials scratch: batch-0 global-head slice of attn_out (8,388,608 B).
    // Dead until global_out overwrites it (after reduce_ctx consumed it).
    float* partials = attn_out + (size_t)LH * SEQ * HD;

    char* ws = (char*)d_ws;
    u16*   ctxT    = (u16*)ws;                               // 131072 B
    float* colsum  = (float*)(ws + 262144);                  // 4096 B
    u16*   Wqk     = (u16*)(ws + 266240);                    // 1 MB
    u16*   Wproj_b = (u16*)(ws + 266240 + 1048576);          // 512 KB
    u16*   kh      = (u16*)(ws + 266240 + 1048576 + 524288); // 33.5 MB
    u16*   attn_b  = kh + (size_t)BATCH * SEQ * DIM;         // 33.5 MB
    u16*   khTg    = attn_b + (size_t)BATCH * SEQ * DIM;     // 16.8 MB (ws ~86 MB)

    const long NX = (long)BATCH * SEQ * DIM;   // 16,777,216

    hipMemsetAsync(colsum, 0, 4096, stream);
    convert_bf16<<<4096, 256, 0, stream>>>(x, xb, NX);
    convert_w3<<<dim3(128, 3), 256, 0, stream>>>(Wq, Wkv, Wproj, Wqk, Wproj_b);

    gemm_qk_tiled<<<dim3(8, 256), 256, 0, stream>>>(xb, Wqk, qh, kh, khTg);
    local_attn<<<dim3(NWIN, 16), 256, 0, stream>>>(qh, kh, attn_out, attn_b);
    ctx_accum<<<dim3(32, 16), 256, 0, stream>>>(khTg, partials, colsum);
    reduce_ctx<<<dim3(4, 16), 256, 0, stream>>>(partials, colsum, ctxT);
    global_out<<<dim3(SEQ / 64, 16), 256, 0, stream>>>(qh, ctxT, attn_out, attn_b);
    proj_gemm_tiled<<<dim3(4, 256), 256, 0, stream>>>(attn_b, Wproj_b, bproj, y);
}